// Round 20
// baseline (2799.036 us; speedup 1.0000x reference)
//
#include <hip/hip_runtime.h>
#include <hip/hip_bf16.h>

#define HID     256
#define AFD     133
#define KA_PAD  160
#define KB_PAD  32
#define MAXNB   16
#define BN_EPS  1e-5f
#define UNC_CAP 8192

typedef __attribute__((ext_vector_type(8))) __bf16 bf16x8;
typedef __attribute__((ext_vector_type(4))) float  f32x4;
typedef unsigned int u32x4 __attribute__((ext_vector_type(4)));
typedef unsigned int u32x2 __attribute__((ext_vector_type(2)));

__device__ __forceinline__ unsigned short f2bf(float x){
  union { __hip_bfloat16 b; unsigned short u; } cv;
  cv.b = __float2bfloat16(x);
  return cv.u;
}
__device__ __forceinline__ float bf2f(unsigned short u){
  union { unsigned int i; float f; } cv;
  cv.i = ((unsigned int)u) << 16;
  return cv.f;
}

__device__ __forceinline__ unsigned swzb(int row, int kbyte, int rowStrideB){
  return (unsigned)(row*rowStrideB + kbyte) ^ (unsigned)((row & 7) << 4);
}

__device__ __forceinline__ f32x4 mfma16(bf16x8 a, bf16x8 b, f32x4 c){
  return __builtin_amdgcn_mfma_f32_16x16x32_bf16(a, b, c, 0, 0, 0);
}

// scalar index into fragment-major weight layout [col_tile][kstep][lane][8]
__device__ __forceinline__ size_t wfidx(int k, int col, int nks){
  return ((size_t)((col>>4)*nks + (k>>5))*64 + (size_t)((((k>>3)&3)<<4) + (col&15)))*8 + (k&7);
}

// ---------------- packing kernels ----------------

__global__ void pack_wfrag(const float* __restrict__ W, unsigned short* __restrict__ WT,
                           int Kreal, int Kpad, int Ncols){
  int total = Ncols * Kpad;
  int nks = Kpad >> 5;
  for(int idx = blockIdx.x*blockDim.x + threadIdx.x; idx < total; idx += gridDim.x*blockDim.x){
    int j    = idx & 7;
    int l    = (idx >> 3) & 63;
    int rest = idx >> 9;
    int ks   = rest % nks;
    int cj   = rest / nks;
    int k    = ks*32 + ((l>>4)<<3) + j;
    int col  = cj*16 + (l & 15);
    float v = (k < Kreal) ? W[(size_t)k*Ncols + col] : 0.f;
    WT[idx] = f2bf(v);
  }
}

__global__ void pack_eb(const float* __restrict__ fb, unsigned short* __restrict__ eb, int E){
  int total = E*16;
  for(int idx = blockIdx.x*blockDim.x + threadIdx.x; idx < total; idx += gridDim.x*blockDim.x){
    int e = idx >> 4, k = idx & 15;
    float v = (k < 15) ? fb[(size_t)e*15 + k] : 0.f;
    eb[idx] = f2bf(v);
  }
}

// ---------------- CSR slot machinery ----------------

__global__ void count_scan(const int* __restrict__ a2b, int* __restrict__ offs_local,
                           int* __restrict__ partials, int N){
  __shared__ int s[256];
  int t = threadIdx.x;
  int a = blockIdx.x*256 + t;
  int c = 0;
  if(a < N){
    const int* ab = a2b + (size_t)a*MAXNB;
#pragma unroll
    for(int j4=0;j4<4;j4++){
      int4 iv = *(const int4*)(ab + j4*4);
      c += (iv.x>0) + (iv.y>0) + (iv.z>0) + (iv.w>0);
    }
  }
  s[t] = c;
  __syncthreads();
  for(int off=1; off<256; off<<=1){
    int u = (t>=off) ? s[t-off] : 0;
    __syncthreads();
    s[t] += u;
    __syncthreads();
  }
  if(a < N) offs_local[a] = s[t] - c;
  if(t == 255) partials[blockIdx.x] = s[255];
}

__global__ void scan_partials(int* __restrict__ partials, int nb, int* __restrict__ total){
  __shared__ int s[512];
  int t = threadIdx.x;
  int v = (t < nb) ? partials[t] : 0;
  s[t] = v;
  __syncthreads();
  for(int off=1; off<512; off<<=1){
    int u = (t>=off) ? s[t-off] : 0;
    __syncthreads();
    s[t] += u;
    __syncthreads();
  }
  if(t < nb) partials[t] = s[t] - v;
  if(t == 511) *total = s[511];
}

__global__ void add_base(const int* __restrict__ offs_local, const int* __restrict__ partials,
                         const int* __restrict__ total, int* __restrict__ offsets, int N){
  for(int i = blockIdx.x*blockDim.x + threadIdx.x; i < N; i += gridDim.x*blockDim.x)
    offsets[i] = offs_local[i] + partials[i >> 8];
  if(blockIdx.x == 0 && threadIdx.x == 0) offsets[N] = *total;
}

__global__ void build_slot(const int* __restrict__ a2b, const int* __restrict__ offsets,
                           int* __restrict__ b2slot, int* __restrict__ slot2b, int N){
  int totalIdx = N*MAXNB;
  for(int idx = blockIdx.x*blockDim.x + threadIdx.x; idx < totalIdx; idx += gridDim.x*blockDim.x){
    int b = a2b[idx];
    if(b > 0){
      int slot = offsets[idx >> 4] + (idx & 15);
      b2slot[b] = slot;
      slot2b[slot] = b;
    }
  }
}

__global__ void reorder_csr(const int* __restrict__ slot2b, const int* __restrict__ total,
                            const unsigned short* __restrict__ eb, const int* __restrict__ b2a,
                            unsigned short* __restrict__ ebC, int* __restrict__ srcC){
  int tot = *total;
  for(int s = blockIdx.x*blockDim.x + threadIdx.x; s < tot; s += gridDim.x*blockDim.x){
    int b = slot2b[s];
    srcC[s] = b2a[b];
    *(uint4*)(ebC + (size_t)s*16)     = *(const uint4*)(eb + (size_t)b*16);
    *(uint4*)(ebC + (size_t)s*16 + 8) = *(const uint4*)(eb + (size_t)b*16 + 8);
  }
}

__global__ void build_unc(const int* __restrict__ b2slot, int* __restrict__ unc, int E){
  for(int e = blockIdx.x*blockDim.x + threadIdx.x; e < E; e += gridDim.x*blockDim.x){
    if(b2slot[e] < 0){
      int p = atomicAdd(&unc[0], 1);
      if(p < UNC_CAP) unc[1+p] = e;
    }
  }
}

// ---------------- misc small kernels ----------------

__global__ void sl_emb_kernel(const float* __restrict__ w1, const float* __restrict__ b1,
                              const float* __restrict__ w2, const float* __restrict__ b2,
                              float* __restrict__ sl){
  int l = blockIdx.x, t = threadIdx.x;
  __shared__ float hid[HID];
  float hv = w1[((size_t)l*16 + 15)*HID + t] + b1[(size_t)l*HID + t];
  hid[t] = hv > 0.f ? hv : 0.f;
  __syncthreads();
  const float* W2 = w2 + (size_t)l*HID*HID;
  float acc = b2[(size_t)l*HID + t];
  for(int k=0;k<HID;k++) acc += hid[k] * W2[(size_t)k*HID + t];
  sl[(size_t)l*HID + t] = acc;
}

// lo = sum over uncovered bonds of (bf16(e_emb+b2) + hbn[b2a]) ; single block
__global__ void leftover_mlp(const unsigned short* __restrict__ eb, const int* __restrict__ b2a,
                             const int* __restrict__ unc,
                             const unsigned short* __restrict__ w1T, const float* __restrict__ b1,
                             const unsigned short* __restrict__ w2T, const float* __restrict__ b2,
                             const unsigned short* __restrict__ hbn, float* __restrict__ lo){
  __shared__ float sEB16[16];
  __shared__ float sh1[HID];
  int t = threadIdx.x;
  int nU = unc[0]; if(nU > UNC_CAP) nU = UNC_CAP;
  float acc = 0.f;
  for(int u=0; u<nU; u++){
    int e = unc[1+u];
    if(t < 16) sEB16[t] = bf2f(eb[(size_t)e*16 + t]);
    __syncthreads();
    float h = b1[t];
#pragma unroll
    for(int k=0;k<16;k++) h += sEB16[k] * bf2f(w1T[wfidx(k, t, KB_PAD>>5)]);
    h = h > 0.f ? h : 0.f;
    sh1[t] = bf2f(f2bf(h));
    __syncthreads();
    float v = b2[t];
    for(int k=0;k<HID;k++) v += sh1[k] * bf2f(w2T[wfidx(k, t, HID>>5)]);
    int src = b2a[e];
    acc += bf2f(f2bf(v)) + bf2f(hbn[(size_t)src*HID + t]);
    __syncthreads();
  }
  lo[t] = acc;
}

// hbn = bf16( BN(h) relu ) for layers >= 1
__global__ void bn_relu_pack(const float* __restrict__ h,
                             const float* __restrict__ musig, const float* __restrict__ gamma,
                             const float* __restrict__ beta,
                             unsigned short* __restrict__ hbn, long total8){
  for(long i = (long)blockIdx.x*blockDim.x + threadIdx.x; i < total8; i += (long)gridDim.x*blockDim.x){
    int c0 = ((int)(i & 31)) << 3;
    f32x4 v0 = __builtin_nontemporal_load(((const f32x4*)h) + i*2);
    f32x4 v1 = __builtin_nontemporal_load(((const f32x4*)h) + i*2 + 1);
    float o[8] = {v0[0],v0[1],v0[2],v0[3],v1[0],v1[1],v1[2],v1[3]};
#pragma unroll
    for(int c=0;c<8;c++){
      float x = gamma[c0+c]*(o[c] - musig[c0+c])*musig[256+c0+c] + beta[c0+c];
      o[c] = x > 0.f ? x : 0.f;
    }
    union { uint4 v; unsigned short us[8]; } pk;
#pragma unroll
    for(int c=0;c<8;c++) pk.us[c] = f2bf(o[c]);
    ((uint4*)hbn)[i] = pk.v;
  }
}

// ---------------- atom embed: hbn0 = bf16(f_atoms @ w_atom) ----------------

__global__ __launch_bounds__(256,2) void atom_embed(
    const float* __restrict__ fat, const unsigned short* __restrict__ wAT,
    unsigned short* __restrict__ hbn, int N)
{
  __shared__ alignas(16) char SM[32768];
  unsigned short* sA = (unsigned short*)SM;
  const int t = threadIdx.x;
  const int m0 = blockIdx.x*64;
  for(int i=t; i<64*KA_PAD; i+=256){
    int row = i / KA_PAD;
    int k   = i - row*KA_PAD;
    int gr  = m0 + row;
    float v = (gr < N && k < AFD) ? fat[(size_t)gr*AFD + k] : 0.f;
    *(unsigned short*)((char*)sA + swzb(row, k*2, KA_PAD*2)) = f2bf(v);
  }
  __syncthreads();
  const int w = t>>6, l = t&63, lg = l>>4, lc = l&15;
  const f32x4 z4 = {0.f,0.f,0.f,0.f};
  f32x4 acc[4][4];
#pragma unroll
  for(int fi=0;fi<4;fi++)
#pragma unroll
    for(int fj=0;fj<4;fj++) acc[fi][fj] = z4;
  for(int k0=0;k0<KA_PAD;k0+=32){
    bf16x8 a[4], b[4];
#pragma unroll
    for(int fi=0;fi<4;fi++)
      a[fi] = *(const bf16x8*)((const char*)sA + swzb(fi*16+lc, (k0+lg*8)*2, KA_PAD*2));
#pragma unroll
    for(int fj=0;fj<4;fj++)
      b[fj] = *(const bf16x8*)(wAT + ((size_t)(w*4+fj)*5 + (k0>>5))*512 + l*8);
#pragma unroll
    for(int fi=0;fi<4;fi++)
#pragma unroll
      for(int fj=0;fj<4;fj++)
        acc[fi][fj] = mfma16(a[fi], b[fj], acc[fi][fj]);
  }
  __syncthreads();
#pragma unroll
  for(int fj=0;fj<4;fj++){
    int col = w*64 + fj*16 + lc;
#pragma unroll
    for(int fi=0;fi<4;fi++)
#pragma unroll
      for(int r=0;r<4;r++){
        int row = fi*16 + lg*4 + r;
        *(unsigned short*)(SM + swzb(row, col*2, 512)) = f2bf(acc[fi][fj][r]);
      }
  }
  __syncthreads();
  for(int c=t; c<2048; c+=256){
    int row = c >> 5, q = c & 31;
    int gr = m0 + row;
    if(gr < N){
      uint4 v = *(const uint4*)(SM + swzb(row, q*16, 512));
      ((uint4*)(hbn + (size_t)gr*HID))[q] = v;
    }
  }
}

// ---------------- hsum_gather: hsum[a] = bf16( hbn[a] + sl (+lo) + sum hbn[srcC[slot]] ) ----------------

__global__ __launch_bounds__(256,8) void hsum_gather(
    const int* __restrict__ offsets, const int* __restrict__ srcC,
    const unsigned short* __restrict__ hbn,
    const float* __restrict__ sl, const float* __restrict__ lo,
    unsigned short* __restrict__ hsum, int N)
{
  const int lane = threadIdx.x & 63;
  const int gw   = (blockIdx.x*blockDim.x + threadIdx.x) >> 6;
  const int nw   = (gridDim.x*blockDim.x) >> 6;
  const int c0   = lane*4;

  for(int a = gw; a < N; a += nw){
    float acc[4];
    {
      union { uint2 v; unsigned short us[4]; } hv;
      hv.v = *(const uint2*)(hbn + (size_t)a*HID + c0);
#pragma unroll
      for(int x=0;x<4;x++) acc[x] = bf2f(hv.us[x]);
    }
#pragma unroll
    for(int x=0;x<4;x++) acc[x] += sl[c0+x];
    if(a == 0){
#pragma unroll
      for(int x=0;x<4;x++) acc[x] += lo[c0+x];
    }
    int s    = offsets[a];
    int send = offsets[a+1];
    for(; s+1 < send; s += 2){
      int src0 = srcC[s], src1 = srcC[s+1];
      union { uint2 v; unsigned short us[4]; } g0v, g1v;
      g0v.v = *(const uint2*)(hbn + (size_t)src0*HID + c0);
      g1v.v = *(const uint2*)(hbn + (size_t)src1*HID + c0);
#pragma unroll
      for(int x=0;x<4;x++) acc[x] += bf2f(g0v.us[x]) + bf2f(g1v.us[x]);
    }
    if(s < send){
      int src0 = srcC[s];
      union { uint2 v; unsigned short us[4]; } gv;
      gv.v = *(const uint2*)(hbn + (size_t)src0*HID + c0);
#pragma unroll
      for(int x=0;x<4;x++) acc[x] += bf2f(gv.us[x]);
    }
    union { u32x2 v; unsigned short us[4]; } pk;
#pragma unroll
    for(int x=0;x<4;x++) pk.us[x] = f2bf(acc[x]);
    __builtin_nontemporal_store(pk.v, (u32x2*)(hsum + (size_t)a*HID + c0));
  }
}

// ---------------- layer_atom: fused, MFMA-based segmented reduce ----------------
// NO __launch_bounds__: allocator takes ~120-128 VGPR (no cap -> no spill;
// LB(,3) caps at 84 and spills ~200MB/dispatch, LB(,2) caps blocks at 2).
// LDS 54272B -> 3 blocks/CU fit (3x54272=162816 <= 163840); VGPR ~120 allows
// 4 waves/SIMD, so occupancy is LDS-limited at 3 blocks/CU (12 waves/CU).
// Phase A: hidsum = sel @ relu(ebC@W1+b1)  (MFMA sel-reduce, ebC dbuf)
// Phase B1: aggr = bf16( hidsum@W2 + deg*b2e + hsum )
// Phase B2: z = mlp(aggr) + BN stats + coalesced z write

__global__ void layer_atom(
    const unsigned short* __restrict__ ebC, const int* __restrict__ offsets,
    const unsigned short* __restrict__ w1T, const float* __restrict__ b1e,
    const unsigned short* __restrict__ w2T, const float* __restrict__ b2e,
    const unsigned short* __restrict__ hsum,
    const unsigned short* __restrict__ m1T, const float* __restrict__ b1n,
    const unsigned short* __restrict__ m2T, const float* __restrict__ b2n,
    float* __restrict__ z, float* __restrict__ stats, int N)
{
  __shared__ alignas(16) char SM[53248];
  // phase A: sEB0 @0 (4KB) | sHT @4096 (32KB: [256 col][64 slot] bf16 swz128)
  //          sSel @36864 (8KB: [64 atom][64 slot] bf16 swz128) | sEB1 @45056 (4KB)
  // phase B: sH @4096 (hidsum/aggr, row-major swz512) | sHD @36864 (16KB)
  // z-write: sZF @0 (33280B)
  unsigned short* sEB0 = (unsigned short*)SM;
  unsigned short* sHT  = (unsigned short*)(SM + 4096);
  unsigned short* sH   = (unsigned short*)(SM + 4096);
  unsigned short* sSel = (unsigned short*)(SM + 36864);
  unsigned short* sHD  = (unsigned short*)(SM + 36864);
  unsigned short* sEB1 = (unsigned short*)(SM + 45056);
  __shared__ int sOff[65];
  __shared__ int sDeg[64];
  const int t  = threadIdx.x;
  const int m0 = blockIdx.x*64;

  if(t < 65) sOff[t] = offsets[min(m0 + t, N)];
  __syncthreads();
  const int sBeg = sOff[0], sEnd = sOff[64];
  if(t < 64) sDeg[t] = sOff[t+1] - sOff[t];

  const int w = t>>6, l = t&63, lg = l>>4, lc = l&15;
  const f32x4 z4 = {0.f,0.f,0.f,0.f};

  // ---- Phase A: hidsum via sel@hid1, accumulated in MFMA C regs ----
  f32x4 hacc[4][4];
#pragma unroll
  for(int fi=0;fi<4;fi++)
#pragma unroll
    for(int fj=0;fj<4;fj++) hacc[fi][fj] = z4;

  {
    const int prow = t >> 2;
    const int pkc  = (t & 3) << 3;

    // prologue: stage first tile into sEB0
    {
      int slot = sBeg + prow;
      u32x4 val = {0,0,0,0};
      if(pkc < 16 && slot < min(sBeg+64, sEnd))
        val = __builtin_nontemporal_load((const u32x4*)(ebC + (size_t)slot*16 + pkc));
      *(u32x4*)((char*)sEB0 + swzb(prow, pkc*2, 64)) = val;
    }

    int cur = 0;
    for(int sb = sBeg; sb < sEnd; sb += 64){
      const int se = min(sb + 64, sEnd);
      __syncthreads();                 // sEB[cur] visible; sHT/sSel free (prev reduce done)
      unsigned short* sEBc = cur ? sEB1 : sEB0;
      unsigned short* sEBn = cur ? sEB0 : sEB1;

      const bool hasNext = (sb + 64 < sEnd);
      u32x4 nv = {0,0,0,0};
      if(hasNext){
        int slot = sb + 64 + prow;
        if(pkc < 16 && slot < min(sb+128, sEnd))
          nv = __builtin_nontemporal_load((const u32x4*)(ebC + (size_t)slot*16 + pkc));
      }

      { // stage-1 MFMA -> hid1 transposed into sHT[col][slot]
        bf16x8 a[4];
#pragma unroll
        for(int fi=0;fi<4;fi++)
          a[fi] = *(const bf16x8*)((const char*)sEBc + swzb(fi*16+lc, lg*16, 64));
#pragma unroll
        for(int fj=0;fj<4;fj++){
          bf16x8 b = *(const bf16x8*)(w1T + (size_t)(w*4+fj)*512 + l*8);
          int col = w*64 + fj*16 + lc;
          float bias = b1e[col];
#pragma unroll
          for(int fi=0;fi<4;fi++){
            f32x4 s1 = mfma16(a[fi], b, z4);
#pragma unroll
            for(int r=0;r<4;r++){
              int slot = fi*16 + lg*4 + r;
              float v = s1[r] + bias;
              v = v > 0.f ? v : 0.f;
              *(unsigned short*)((char*)sHT + swzb(col, slot*2, 128)) = f2bf(v);
            }
          }
        }
      }

      // sel rows: thread t<64 owns atom-local row t (race-free full-row write)
      if(t < 64){
        int lo = max(sOff[t], sb) - sb;
        int hi = min(sOff[t+1], se) - sb;
#pragma unroll
        for(int g=0; g<8; g++){
          union { u32x4 v; unsigned short us[8]; } pk;
#pragma unroll
          for(int j=0;j<8;j++){
            int s = g*8 + j;
            pk.us[j] = (s >= lo && s < hi) ? (unsigned short)0x3F80 : (unsigned short)0;
          }
          *(u32x4*)((char*)sSel + swzb(t, g*16, 128)) = pk.v;
        }
      }

      if(hasNext)
        *(u32x4*)((char*)sEBn + swzb(prow, pkc*2, 64)) = nv;
      __syncthreads();                 // sHT + sSel ready

      // reduce: hacc += sel @ hid1
#pragma unroll
      for(int ks=0; ks<2; ks++){
        bf16x8 as[4], bh[4];
#pragma unroll
        for(int fi=0;fi<4;fi++)
          as[fi] = *(const bf16x8*)((const char*)sSel + swzb(fi*16+lc, (ks*32+lg*8)*2, 128));
#pragma unroll
        for(int fj=0;fj<4;fj++)
          bh[fj] = *(const bf16x8*)((const char*)sHT + swzb(w*64+fj*16+lc, (ks*32+lg*8)*2, 128));
#pragma unroll
        for(int fi=0;fi<4;fi++)
#pragma unroll
          for(int fj=0;fj<4;fj++)
            hacc[fi][fj] = mfma16(as[fi], bh[fj], hacc[fi][fj]);
      }
      cur ^= 1;
    }
  }
  __syncthreads();                     // last reduce done; sHT region becomes sH

  // write hidsum (bf16) into sH row-major [atom][col]
#pragma unroll
  for(int fj=0;fj<4;fj++){
    int col = w*64 + fj*16 + lc;
#pragma unroll
    for(int fi=0;fi<4;fi++)
#pragma unroll
      for(int r=0;r<4;r++){
        int row = fi*16 + lg*4 + r;
        *(unsigned short*)((char*)sH + swzb(row, col*2, 512)) = f2bf(hacc[fi][fj][r]);
      }
  }
  __syncthreads();

  // ---- Phase B1: aggr = bf16( hidsum@W2 + deg*b2e + hsum ) ----
  {
    f32x4 zacc[4][4];
#pragma unroll
    for(int fi=0;fi<4;fi++)
#pragma unroll
      for(int fj=0;fj<4;fj++) zacc[fi][fj] = z4;
    for(int k0=0;k0<256;k0+=32){
      bf16x8 a[4], b[4];
#pragma unroll
      for(int fi=0;fi<4;fi++)
        a[fi] = *(const bf16x8*)((const char*)sH + swzb(fi*16+lc, (k0+lg*8)*2, 512));
#pragma unroll
      for(int fj=0;fj<4;fj++)
        b[fj] = *(const bf16x8*)(w2T + ((size_t)(w*4+fj)*8 + (k0>>5))*512 + l*8);
#pragma unroll
      for(int fi=0;fi<4;fi++)
#pragma unroll
        for(int fj=0;fj<4;fj++)
          zacc[fi][fj] = mfma16(a[fi], b[fj], zacc[fi][fj]);
    }
    __syncthreads();   // done reading hidsum from sH

    // stage hsum tile into sH
    for(int i=t; i<2048; i+=256){
      int row = i >> 5, q = i & 31;
      int gr = m0 + row;
      u32x4 v = {0,0,0,0};
      if(gr < N) v = __builtin_nontemporal_load(((const u32x4*)(hsum + (size_t)gr*HID)) + q);
      *(u32x4*)((char*)sH + swzb(row, q*16, 512)) = v;
    }
    __syncthreads();

    // combine in LDS: sH = bf16( zacc + deg*b2e + hsum )
#pragma unroll
    for(int fj=0;fj<4;fj++){
      int col = w*64 + fj*16 + lc;
      float b2c = b2e[col];
#pragma unroll
      for(int fi=0;fi<4;fi++)
#pragma unroll
        for(int r=0;r<4;r++){
          int row = fi*16 + lg*4 + r;
          unsigned short* p = (unsigned short*)((char*)sH + swzb(row, col*2, 512));
          float v = zacc[fi][fj][r] + (float)sDeg[row]*b2c + bf2f(*p);
          *p = f2bf(v);
        }
    }
  }
  __syncthreads();

  // ---- Phase B2: node MLP from sH (aggr) ----
  f32x4 nacc[4][4];
#pragma unroll
  for(int fi=0;fi<4;fi++)
#pragma unroll
    for(int fj=0;fj<4;fj++) nacc[fi][fj] = z4;

  for(int c=0;c<4;c++){
    f32x4 h1[4][2];
#pragma unroll
    for(int fi=0;fi<4;fi++){ h1[fi][0] = z4; h1[fi][1] = z4; }
    for(int k0=0;k0<256;k0+=32){
      bf16x8 a[4];
#pragma unroll
      for(int fi=0;fi<4;fi++)
        a[fi] = *(const bf16x8*)((const char*)sH + swzb(fi*16+lc, (k0+lg*8)*2, 512));
#pragma unroll
      for(int fj=0;fj<2;fj++){
        bf16x8 b = *(const bf16x8*)(m1T + ((size_t)(c*8 + w*2 + fj)*8 + (k0>>5))*512 + l*8);
#pragma unroll
        for(int fi=0;fi<4;fi++)
          h1[fi][fj] = mfma16(a[fi], b, h1[fi][fj]);
      }
    }
    __syncthreads();
#pragma unroll
    for(int fj=0;fj<2;fj++){
      int col  = c*128 + w*32 + fj*16 + lc;
      int lcol = w*32 + fj*16 + lc;
      float bias = b1n[col];
#pragma unroll
      for(int fi=0;fi<4;fi++)
#pragma unroll
        for(int r=0;r<4;r++){
          int row = fi*16 + lg*4 + r;
          float v = h1[fi][fj][r] + bias;
          v = v > 0.f ? v : 0.f;
          *(unsigned short*)((char*)sHD + swzb(row, lcol*2, 256)) = f2bf(v);
        }
    }
    __syncthreads();
    for(int k0=0;k0<128;k0+=32){
      bf16x8 a[4], b[4];
#pragma unroll
      for(int fi=0;fi<4;fi++)
        a[fi] = *(const bf16x8*)((const char*)sHD + swzb(fi*16+lc, (k0+lg*8)*2, 256));
#pragma unroll
      for(int fj=0;fj<4;fj++)
        b[fj] = *(const bf16x8*)(m2T + ((size_t)(w*4+fj)*16 + c*4 + (k0>>5))*512 + l*8);
#pragma unroll
      for(int fi=0;fi<4;fi++)
#pragma unroll
        for(int fj=0;fj<4;fj++)
          nacc[fi][fj] = mfma16(a[fi], b[fj], nacc[fi][fj]);
    }
  }

  // BN stats
  float bb[4];
#pragma unroll
  for(int fj=0;fj<4;fj++){
    int col = w*64 + fj*16 + lc;
    bb[fj] = b2n[col];
    float s1 = 0.f, s2 = 0.f;
#pragma unroll
    for(int fi=0;fi<4;fi++)
#pragma unroll
      for(int r=0;r<4;r++){
        int gr = m0 + fi*16 + lg*4 + r;
        float v = nacc[fi][fj][r] + bb[fj];
        if(gr < N){ s1 += v; s2 += v*v; }
      }
    s1 += __shfl_xor(s1, 16, 64); s1 += __shfl_xor(s1, 32, 64);
    s2 += __shfl_xor(s2, 16, 64); s2 += __shfl_xor(s2, 32, 64);
    if(lg == 0){
      atomicAdd(&stats[col],       s1);
      atomicAdd(&stats[HID + col], s2);
    }
  }

  // z write restaged through LDS
  float* sZF = (float*)SM;   // [32][260] f32 = 33280 B
#pragma unroll
  for(int half=0; half<2; half++){
    __syncthreads();
#pragma unroll
    for(int fj=0;fj<4;fj++){
      int col = w*64 + fj*16 + lc;
#pragma unroll
      for(int fp=0;fp<2;fp++){
        int fi = half*2 + fp;
#pragma unroll
        for(int r=0;r<4;r++){
          int row32 = fp*16 + lg*4 + r;
          sZF[row32*260 + col] = nacc[fi][fj][r] + bb[fj];
        }
      }
    }
    __syncthreads();
    for(int i=t; i<2048; i+=256){
      int row = i >> 6, seg = i & 63;
      int gr = m0 + half*32 + row;
      if(gr < N){
        u32x4 v = *(const u32x4*)(sZF + row*260 + seg*4);
        __builtin_nontemporal_store(v, (u32x4*)(z + (size_t)gr*HID + seg*4));
      }
    }
  }
}

__global__ void stats_fin(const float* __restrict__ stats, float* __restrict__ musig, float invN){
  int c = threadIdx.x;
  float mu  = stats[c] * invN;
  float var = stats[HID + c] * invN - mu*mu;
  musig[c]       = mu;
  musig[HID + c] = rsqrtf(var + BN_EPS);
}

__global__ void final_bn(float* __restrict__ out, const float* __restrict__ musig,
                         const float* __restrict__ gamma, const float* __restrict__ beta,
                         long total4){
  for(long i = (long)blockIdx.x*blockDim.x + threadIdx.x; i < total4; i += (long)gridDim.x*blockDim.x){
    int c0 = ((int)(i & 63)) << 2;
    float4 v = ((const float4*)out)[i];
    float o[4] = {v.x, v.y, v.z, v.w};
#pragma unroll
    for(int c=0;c<4;c++)
      o[c] = gamma[c0+c]*(o[c] - musig[c0+c])*musig[256+c0+c] + beta[c0+c];
    float4 ov = {o[0], o[1], o[2], o[3]};
    ((float4*)out)[i] = ov;
  }
}

// ---------------- host ----------------
// Workspace ~190 MB. Intermediate z lives in d_out.

extern "C" void kernel_launch(void* const* d_in, const int* in_sizes, int n_in,
                              void* d_out, int out_size, void* d_ws, size_t ws_size,
                              hipStream_t stream)
{
  const float* f_atoms = (const float*)d_in[0];
  const float* f_bonds = (const float*)d_in[1];
  const int*   a2b     = (const int*)d_in[2];
  const int*   b2a     = (const int*)d_in[3];
  const float* w_atom  = (const float*)d_in[6];
  const float* wb_w1   = (const float*)d_in[7];
  const float* wb_b1   = (const float*)d_in[8];
  const float* wb_w2   = (const float*)d_in[9];
  const float* wb_b2   = (const float*)d_in[10];
  const float* mlp_w1  = (const float*)d_in[11];
  const float* mlp_b1  = (const float*)d_in[12];
  const float* mlp_w2  = (const float*)d_in[13];
  const float* mlp_b2  = (const float*)d_in[14];
  const float* bn_g    = (const float*)d_in[15];
  const float* bn_b    = (const float*)d_in[16];
  const int N = in_sizes[0] / AFD;
  const int E = in_sizes[3];
  float* out = (float*)d_out;
  (void)n_in; (void)out_size; (void)ws_size;

  char* ws = (char*)d_ws;
  size_t off = 0;
  auto alloc = [&](size_t bytes)->char* {
    char* p = ws + off; off += (bytes + 255) & ~(size_t)255; return p;
  };
  unsigned short* hbn   = (unsigned short*)alloc((size_t)N*HID*2);
  unsigned short* hsum  = (unsigned short*)alloc((size_t)N*HID*2);
  unsigned short* eb    = (unsigned short*)alloc((size_t)E*16*2);
  unsigned short* ebC   = (unsigned short*)alloc((size_t)E*16*2);
  int* srcC             = (int*)alloc((size_t)E*4);
  int* b2slot           = (int*)alloc((size_t)E*4);
  int* slot2b           = (int*)alloc((size_t)E*4);
  int* offsets          = (int*)alloc((size_t)(N+1)*4);
  int* offs_local       = (int*)alloc((size_t)N*4);
  int* partials         = (int*)alloc((size_t)512*4);
  int* total            = (int*)alloc((size_t)4);
  int* unc              = (int*)alloc((size_t)(1+UNC_CAP)*4);
  unsigned short* wAT   = (unsigned short*)alloc((size_t)HID*KA_PAD*2);
  unsigned short* w1T   = (unsigned short*)alloc((size_t)3*HID*KB_PAD*2);
  unsigned short* w2T   = (unsigned short*)alloc((size_t)3*HID*HID*2);
  unsigned short* m1T   = (unsigned short*)alloc((size_t)3*512*HID*2);
  unsigned short* m2T   = (unsigned short*)alloc((size_t)3*HID*512*2);
  float* sl             = (float*)alloc((size_t)3*HID*4);
  float* stats          = (float*)alloc((size_t)3*512*4);
  float* musig          = (float*)alloc((size_t)3*512*4);
  float* lo             = (float*)alloc((size_t)3*HID*4);

  hipMemsetAsync(stats,  0,    (size_t)3*512*4, stream);
  hipMemsetAsync(b2slot, 0xFF, (size_t)E*4, stream);
  hipMemsetAsync(unc,    0,    (size_t)(1+UNC_CAP)*4, stream);

  auto cdiv = [](long a, long b){ return (int)((a + b - 1)/b); };
  const int nb = cdiv(N, 256);

  count_scan<<<nb,256,0,stream>>>(a2b, offs_local, partials, N);
  scan_partials<<<1,512,0,stream>>>(partials, nb, total);
  add_base<<<512,256,0,stream>>>(offs_local, partials, total, offsets, N);
  build_slot<<<2048,256,0,stream>>>(a2b, offsets, b2slot, slot2b, N);
  pack_eb<<<2048,256,0,stream>>>(f_bonds, eb, E);
  reorder_csr<<<2048,256,0,stream>>>(slot2b, total, eb, b2a, ebC, srcC);
  build_unc<<<2048,256,0,stream>>>(b2slot, unc, E);

  pack_wfrag<<<cdiv((long)HID*KA_PAD,256),256,0,stream>>>(w_atom, wAT, AFD, KA_PAD, HID);
  for(int l=0;l<3;l++){
    pack_wfrag<<<cdiv((long)HID*KB_PAD,256),256,0,stream>>>(wb_w1 + (size_t)l*16*HID,  w1T + (size_t)l*HID*KB_PAD, 16,  KB_PAD, HID);
    pack_wfrag<<<cdiv((long)HID*HID,256),256,0,stream>>>(wb_w2 + (size_t)l*HID*HID,  w2T + (size_t)l*HID*HID,  HID, HID, HID);
    pack_wfrag<<<cdiv((long)512*HID,256),256,0,stream>>>(mlp_w1 + (size_t)l*HID*512, m1T + (size_t)l*512*HID,  HID, HID, 512);
    pack_wfrag<<<cdiv((long)HID*512,256),256,0,stream>>>(mlp_w2 + (size_t)l*512*HID, m2T + (size_t)l*HID*512,  512, 512, HID);
  }
  sl_emb_kernel<<<3,256,0,stream>>>(wb_w1, wb_b1, wb_w2, wb_b2, sl);

  atom_embed<<<cdiv(N,64),256,0,stream>>>(f_atoms, wAT, hbn, N);

  for(int l=0;l<3;l++){
    if(l > 0){
      bn_relu_pack<<<2048,256,0,stream>>>(out, musig + (size_t)(l-1)*512,
          bn_g + (size_t)(l-1)*HID, bn_b + (size_t)(l-1)*HID, hbn, (long)N*32);
    }
    leftover_mlp<<<1,256,0,stream>>>(eb, b2a, unc,
        w1T + (size_t)l*HID*KB_PAD, wb_b1 + (size_t)l*HID,
        w2T + (size_t)l*HID*HID,    wb_b2 + (size_t)l*HID,
        hbn, lo + (size_t)l*HID);
    hsum_gather<<<2048,256,0,stream>>>(offsets, srcC, hbn,
        sl + (size_t)l*HID, lo + (size_t)l*HID, hsum, N);
    layer_atom<<<cdiv(N,64),256,0,stream>>>(ebC, offsets,
        w1T + (size_t)l*HID*KB_PAD, wb_b1 + (size_t)l*HID,
        w2T + (size_t)l*HID*HID,    wb_b2 + (size_t)l*HID,
        hsum,
        m1T + (size_t)l*512*HID, mlp_b1 + (size_t)l*512,
        m2T + (size_t)l*HID*512, mlp_b2 + (size_t)l*HID,
        out, stats + (size_t)l*512, N);
    stats_fin<<<1,256,0,stream>>>(stats + (size_t)l*512, musig + (size_t)l*512, 1.0f/(float)N);
  }
  final_bn<<<2048,256,0,stream>>>(out, musig + 2*512, bn_g + 2*HID, bn_b + 2*HID, (long)N*64);
}

// Round 21
// 1184.744 us; speedup vs baseline: 2.3626x; 2.3626x over previous
//
#include <hip/hip_runtime.h>
#include <hip/hip_bf16.h>

#define HID     256
#define AFD     133
#define KA_PAD  160
#define KB_PAD  32
#define MAXNB   16
#define BN_EPS  1e-5f
#define UNC_CAP 8192

typedef __attribute__((ext_vector_type(8))) __bf16 bf16x8;
typedef __attribute__((ext_vector_type(4))) float  f32x4;
typedef unsigned int u32x4 __attribute__((ext_vector_type(4)));
typedef unsigned int u32x2 __attribute__((ext_vector_type(2)));

__device__ __forceinline__ unsigned short f2bf(float x){
  union { __hip_bfloat16 b; unsigned short u; } cv;
  cv.b = __float2bfloat16(x);
  return cv.u;
}
__device__ __forceinline__ float bf2f(unsigned short u){
  union { unsigned int i; float f; } cv;
  cv.i = ((unsigned int)u) << 16;
  return cv.f;
}

__device__ __forceinline__ unsigned swzb(int row, int kbyte, int rowStrideB){
  return (unsigned)(row*rowStrideB + kbyte) ^ (unsigned)((row & 7) << 4);
}

__device__ __forceinline__ f32x4 mfma16(bf16x8 a, bf16x8 b, f32x4 c){
  return __builtin_amdgcn_mfma_f32_16x16x32_bf16(a, b, c, 0, 0, 0);
}

// scalar index into fragment-major weight layout [col_tile][kstep][lane][8]
__device__ __forceinline__ size_t wfidx(int k, int col, int nks){
  return ((size_t)((col>>4)*nks + (k>>5))*64 + (size_t)((((k>>3)&3)<<4) + (col&15)))*8 + (k&7);
}

// ---------------- packing kernels ----------------

__global__ void pack_wfrag(const float* __restrict__ W, unsigned short* __restrict__ WT,
                           int Kreal, int Kpad, int Ncols){
  int total = Ncols * Kpad;
  int nks = Kpad >> 5;
  for(int idx = blockIdx.x*blockDim.x + threadIdx.x; idx < total; idx += gridDim.x*blockDim.x){
    int j    = idx & 7;
    int l    = (idx >> 3) & 63;
    int rest = idx >> 9;
    int ks   = rest % nks;
    int cj   = rest / nks;
    int k    = ks*32 + ((l>>4)<<3) + j;
    int col  = cj*16 + (l & 15);
    float v = (k < Kreal) ? W[(size_t)k*Ncols + col] : 0.f;
    WT[idx] = f2bf(v);
  }
}

__global__ void pack_eb(const float* __restrict__ fb, unsigned short* __restrict__ eb, int E){
  int total = E*16;
  for(int idx = blockIdx.x*blockDim.x + threadIdx.x; idx < total; idx += gridDim.x*blockDim.x){
    int e = idx >> 4, k = idx & 15;
    float v = (k < 15) ? fb[(size_t)e*15 + k] : 0.f;
    eb[idx] = f2bf(v);
  }
}

// ---------------- CSR slot machinery ----------------

__global__ void count_scan(const int* __restrict__ a2b, int* __restrict__ offs_local,
                           int* __restrict__ partials, int N){
  __shared__ int s[256];
  int t = threadIdx.x;
  int a = blockIdx.x*256 + t;
  int c = 0;
  if(a < N){
    const int* ab = a2b + (size_t)a*MAXNB;
#pragma unroll
    for(int j4=0;j4<4;j4++){
      int4 iv = *(const int4*)(ab + j4*4);
      c += (iv.x>0) + (iv.y>0) + (iv.z>0) + (iv.w>0);
    }
  }
  s[t] = c;
  __syncthreads();
  for(int off=1; off<256; off<<=1){
    int u = (t>=off) ? s[t-off] : 0;
    __syncthreads();
    s[t] += u;
    __syncthreads();
  }
  if(a < N) offs_local[a] = s[t] - c;
  if(t == 255) partials[blockIdx.x] = s[255];
}

__global__ void scan_partials(int* __restrict__ partials, int nb, int* __restrict__ total){
  __shared__ int s[512];
  int t = threadIdx.x;
  int v = (t < nb) ? partials[t] : 0;
  s[t] = v;
  __syncthreads();
  for(int off=1; off<512; off<<=1){
    int u = (t>=off) ? s[t-off] : 0;
    __syncthreads();
    s[t] += u;
    __syncthreads();
  }
  if(t < nb) partials[t] = s[t] - v;
  if(t == 511) *total = s[511];
}

__global__ void add_base(const int* __restrict__ offs_local, const int* __restrict__ partials,
                         const int* __restrict__ total, int* __restrict__ offsets, int N){
  for(int i = blockIdx.x*blockDim.x + threadIdx.x; i < N; i += gridDim.x*blockDim.x)
    offsets[i] = offs_local[i] + partials[i >> 8];
  if(blockIdx.x == 0 && threadIdx.x == 0) offsets[N] = *total;
}

__global__ void build_slot(const int* __restrict__ a2b, const int* __restrict__ offsets,
                           int* __restrict__ b2slot, int* __restrict__ slot2b, int N){
  int totalIdx = N*MAXNB;
  for(int idx = blockIdx.x*blockDim.x + threadIdx.x; idx < totalIdx; idx += gridDim.x*blockDim.x){
    int b = a2b[idx];
    if(b > 0){
      int slot = offsets[idx >> 4] + (idx & 15);
      b2slot[b] = slot;
      slot2b[slot] = b;
    }
  }
}

__global__ void reorder_csr(const int* __restrict__ slot2b, const int* __restrict__ total,
                            const unsigned short* __restrict__ eb, const int* __restrict__ b2a,
                            unsigned short* __restrict__ ebC, int* __restrict__ srcC){
  int tot = *total;
  for(int s = blockIdx.x*blockDim.x + threadIdx.x; s < tot; s += gridDim.x*blockDim.x){
    int b = slot2b[s];
    srcC[s] = b2a[b];
    *(uint4*)(ebC + (size_t)s*16)     = *(const uint4*)(eb + (size_t)b*16);
    *(uint4*)(ebC + (size_t)s*16 + 8) = *(const uint4*)(eb + (size_t)b*16 + 8);
  }
}

__global__ void build_unc(const int* __restrict__ b2slot, int* __restrict__ unc, int E){
  for(int e = blockIdx.x*blockDim.x + threadIdx.x; e < E; e += gridDim.x*blockDim.x){
    if(b2slot[e] < 0){
      int p = atomicAdd(&unc[0], 1);
      if(p < UNC_CAP) unc[1+p] = e;
    }
  }
}

// ---------------- misc small kernels ----------------

__global__ void sl_emb_kernel(const float* __restrict__ w1, const float* __restrict__ b1,
                              const float* __restrict__ w2, const float* __restrict__ b2,
                              float* __restrict__ sl){
  int l = blockIdx.x, t = threadIdx.x;
  __shared__ float hid[HID];
  float hv = w1[((size_t)l*16 + 15)*HID + t] + b1[(size_t)l*HID + t];
  hid[t] = hv > 0.f ? hv : 0.f;
  __syncthreads();
  const float* W2 = w2 + (size_t)l*HID*HID;
  float acc = b2[(size_t)l*HID + t];
  for(int k=0;k<HID;k++) acc += hid[k] * W2[(size_t)k*HID + t];
  sl[(size_t)l*HID + t] = acc;
}

// lo = sum over uncovered bonds of (bf16(e_emb+b2) + hbn[b2a]) ; single block
__global__ void leftover_mlp(const unsigned short* __restrict__ eb, const int* __restrict__ b2a,
                             const int* __restrict__ unc,
                             const unsigned short* __restrict__ w1T, const float* __restrict__ b1,
                             const unsigned short* __restrict__ w2T, const float* __restrict__ b2,
                             const unsigned short* __restrict__ hbn, float* __restrict__ lo){
  __shared__ float sEB16[16];
  __shared__ float sh1[HID];
  int t = threadIdx.x;
  int nU = unc[0]; if(nU > UNC_CAP) nU = UNC_CAP;
  float acc = 0.f;
  for(int u=0; u<nU; u++){
    int e = unc[1+u];
    if(t < 16) sEB16[t] = bf2f(eb[(size_t)e*16 + t]);
    __syncthreads();
    float h = b1[t];
#pragma unroll
    for(int k=0;k<16;k++) h += sEB16[k] * bf2f(w1T[wfidx(k, t, KB_PAD>>5)]);
    h = h > 0.f ? h : 0.f;
    sh1[t] = bf2f(f2bf(h));
    __syncthreads();
    float v = b2[t];
    for(int k=0;k<HID;k++) v += sh1[k] * bf2f(w2T[wfidx(k, t, HID>>5)]);
    int src = b2a[e];
    acc += bf2f(f2bf(v)) + bf2f(hbn[(size_t)src*HID + t]);
    __syncthreads();
  }
  lo[t] = acc;
}

// hbn = bf16( BN(h) relu ) for layers >= 1
__global__ void bn_relu_pack(const float* __restrict__ h,
                             const float* __restrict__ musig, const float* __restrict__ gamma,
                             const float* __restrict__ beta,
                             unsigned short* __restrict__ hbn, long total8){
  for(long i = (long)blockIdx.x*blockDim.x + threadIdx.x; i < total8; i += (long)gridDim.x*blockDim.x){
    int c0 = ((int)(i & 31)) << 3;
    f32x4 v0 = __builtin_nontemporal_load(((const f32x4*)h) + i*2);
    f32x4 v1 = __builtin_nontemporal_load(((const f32x4*)h) + i*2 + 1);
    float o[8] = {v0[0],v0[1],v0[2],v0[3],v1[0],v1[1],v1[2],v1[3]};
#pragma unroll
    for(int c=0;c<8;c++){
      float x = gamma[c0+c]*(o[c] - musig[c0+c])*musig[256+c0+c] + beta[c0+c];
      o[c] = x > 0.f ? x : 0.f;
    }
    union { uint4 v; unsigned short us[8]; } pk;
#pragma unroll
    for(int c=0;c<8;c++) pk.us[c] = f2bf(o[c]);
    ((uint4*)hbn)[i] = pk.v;
  }
}

// ---------------- atom embed: hbn0 = bf16(f_atoms @ w_atom) ----------------

__global__ __launch_bounds__(256,2) void atom_embed(
    const float* __restrict__ fat, const unsigned short* __restrict__ wAT,
    unsigned short* __restrict__ hbn, int N)
{
  __shared__ alignas(16) char SM[32768];
  unsigned short* sA = (unsigned short*)SM;
  const int t = threadIdx.x;
  const int m0 = blockIdx.x*64;
  for(int i=t; i<64*KA_PAD; i+=256){
    int row = i / KA_PAD;
    int k   = i - row*KA_PAD;
    int gr  = m0 + row;
    float v = (gr < N && k < AFD) ? fat[(size_t)gr*AFD + k] : 0.f;
    *(unsigned short*)((char*)sA + swzb(row, k*2, KA_PAD*2)) = f2bf(v);
  }
  __syncthreads();
  const int w = t>>6, l = t&63, lg = l>>4, lc = l&15;
  const f32x4 z4 = {0.f,0.f,0.f,0.f};
  f32x4 acc[4][4];
#pragma unroll
  for(int fi=0;fi<4;fi++)
#pragma unroll
    for(int fj=0;fj<4;fj++) acc[fi][fj] = z4;
  for(int k0=0;k0<KA_PAD;k0+=32){
    bf16x8 a[4], b[4];
#pragma unroll
    for(int fi=0;fi<4;fi++)
      a[fi] = *(const bf16x8*)((const char*)sA + swzb(fi*16+lc, (k0+lg*8)*2, KA_PAD*2));
#pragma unroll
    for(int fj=0;fj<4;fj++)
      b[fj] = *(const bf16x8*)(wAT + ((size_t)(w*4+fj)*5 + (k0>>5))*512 + l*8);
#pragma unroll
    for(int fi=0;fi<4;fi++)
#pragma unroll
      for(int fj=0;fj<4;fj++)
        acc[fi][fj] = mfma16(a[fi], b[fj], acc[fi][fj]);
  }
  __syncthreads();
#pragma unroll
  for(int fj=0;fj<4;fj++){
    int col = w*64 + fj*16 + lc;
#pragma unroll
    for(int fi=0;fi<4;fi++)
#pragma unroll
      for(int r=0;r<4;r++){
        int row = fi*16 + lg*4 + r;
        *(unsigned short*)(SM + swzb(row, col*2, 512)) = f2bf(acc[fi][fj][r]);
      }
  }
  __syncthreads();
  for(int c=t; c<2048; c+=256){
    int row = c >> 5, q = c & 31;
    int gr = m0 + row;
    if(gr < N){
      uint4 v = *(const uint4*)(SM + swzb(row, q*16, 512));
      ((uint4*)(hbn + (size_t)gr*HID))[q] = v;
    }
  }
}

// ---------------- hsum_gather: hsum[a] = bf16( hbn[a] + sl (+lo) + sum hbn[srcC[slot]] ) ----------------

__global__ __launch_bounds__(256,8) void hsum_gather(
    const int* __restrict__ offsets, const int* __restrict__ srcC,
    const unsigned short* __restrict__ hbn,
    const float* __restrict__ sl, const float* __restrict__ lo,
    unsigned short* __restrict__ hsum, int N)
{
  const int lane = threadIdx.x & 63;
  const int gw   = (blockIdx.x*blockDim.x + threadIdx.x) >> 6;
  const int nw   = (gridDim.x*blockDim.x) >> 6;
  const int c0   = lane*4;

  for(int a = gw; a < N; a += nw){
    float acc[4];
    {
      union { uint2 v; unsigned short us[4]; } hv;
      hv.v = *(const uint2*)(hbn + (size_t)a*HID + c0);
#pragma unroll
      for(int x=0;x<4;x++) acc[x] = bf2f(hv.us[x]);
    }
#pragma unroll
    for(int x=0;x<4;x++) acc[x] += sl[c0+x];
    if(a == 0){
#pragma unroll
      for(int x=0;x<4;x++) acc[x] += lo[c0+x];
    }
    int s    = offsets[a];
    int send = offsets[a+1];
    for(; s+1 < send; s += 2){
      int src0 = srcC[s], src1 = srcC[s+1];
      union { uint2 v; unsigned short us[4]; } g0v, g1v;
      g0v.v = *(const uint2*)(hbn + (size_t)src0*HID + c0);
      g1v.v = *(const uint2*)(hbn + (size_t)src1*HID + c0);
#pragma unroll
      for(int x=0;x<4;x++) acc[x] += bf2f(g0v.us[x]) + bf2f(g1v.us[x]);
    }
    if(s < send){
      int src0 = srcC[s];
      union { uint2 v; unsigned short us[4]; } gv;
      gv.v = *(const uint2*)(hbn + (size_t)src0*HID + c0);
#pragma unroll
      for(int x=0;x<4;x++) acc[x] += bf2f(gv.us[x]);
    }
    union { u32x2 v; unsigned short us[4]; } pk;
#pragma unroll
    for(int x=0;x<4;x++) pk.us[x] = f2bf(acc[x]);
    __builtin_nontemporal_store(pk.v, (u32x2*)(hsum + (size_t)a*HID + c0));
  }
}

// ---------------- layer_atom: fused, MFMA-based segmented reduce ----------------
// LB(256,2) — the ONLY working register budget point (proven R15-R19):
//   no LB        -> compiler targets 64 VGPR -> catastrophic spill (R19)
//   LB(256,3)    -> 84 VGPR cap              -> spill (~200MB/dispatch, R12-R14)
//   LB(256,2)    -> 128 cap, 120 used        -> clean (WRITE == z exactly)
// Phase A: hidsum = sel @ relu(ebC@W1+b1)  (MFMA sel-reduce, ebC dbuf)
// Phase B1: aggr = bf16( hidsum@W2 + deg*b2e + hsum )
// Phase B2: z = mlp(aggr) + BN stats + coalesced z write

__global__ __launch_bounds__(256,2) void layer_atom(
    const unsigned short* __restrict__ ebC, const int* __restrict__ offsets,
    const unsigned short* __restrict__ w1T, const float* __restrict__ b1e,
    const unsigned short* __restrict__ w2T, const float* __restrict__ b2e,
    const unsigned short* __restrict__ hsum,
    const unsigned short* __restrict__ m1T, const float* __restrict__ b1n,
    const unsigned short* __restrict__ m2T, const float* __restrict__ b2n,
    float* __restrict__ z, float* __restrict__ stats, int N)
{
  __shared__ alignas(16) char SM[53248];
  // phase A: sEB0 @0 (4KB) | sHT @4096 (32KB: [256 col][64 slot] bf16 swz128)
  //          sSel @36864 (8KB: [64 atom][64 slot] bf16 swz128) | sEB1 @45056 (4KB)
  // phase B: sH @4096 (hidsum/aggr, row-major swz512) | sHD @36864 (16KB)
  // z-write: sZF @0 (33280B)
  unsigned short* sEB0 = (unsigned short*)SM;
  unsigned short* sHT  = (unsigned short*)(SM + 4096);
  unsigned short* sH   = (unsigned short*)(SM + 4096);
  unsigned short* sSel = (unsigned short*)(SM + 36864);
  unsigned short* sHD  = (unsigned short*)(SM + 36864);
  unsigned short* sEB1 = (unsigned short*)(SM + 45056);
  __shared__ int sOff[65];
  __shared__ int sDeg[64];
  const int t  = threadIdx.x;
  const int m0 = blockIdx.x*64;

  if(t < 65) sOff[t] = offsets[min(m0 + t, N)];
  __syncthreads();
  const int sBeg = sOff[0], sEnd = sOff[64];
  if(t < 64) sDeg[t] = sOff[t+1] - sOff[t];

  const int w = t>>6, l = t&63, lg = l>>4, lc = l&15;
  const f32x4 z4 = {0.f,0.f,0.f,0.f};

  // ---- Phase A: hidsum via sel@hid1, accumulated in MFMA C regs ----
  f32x4 hacc[4][4];
#pragma unroll
  for(int fi=0;fi<4;fi++)
#pragma unroll
    for(int fj=0;fj<4;fj++) hacc[fi][fj] = z4;

  {
    const int prow = t >> 2;
    const int pkc  = (t & 3) << 3;

    // prologue: stage first tile into sEB0
    {
      int slot = sBeg + prow;
      u32x4 val = {0,0,0,0};
      if(pkc < 16 && slot < min(sBeg+64, sEnd))
        val = __builtin_nontemporal_load((const u32x4*)(ebC + (size_t)slot*16 + pkc));
      *(u32x4*)((char*)sEB0 + swzb(prow, pkc*2, 64)) = val;
    }

    int cur = 0;
    for(int sb = sBeg; sb < sEnd; sb += 64){
      const int se = min(sb + 64, sEnd);
      __syncthreads();                 // sEB[cur] visible; sHT/sSel free (prev reduce done)
      unsigned short* sEBc = cur ? sEB1 : sEB0;
      unsigned short* sEBn = cur ? sEB0 : sEB1;

      const bool hasNext = (sb + 64 < sEnd);
      u32x4 nv = {0,0,0,0};
      if(hasNext){
        int slot = sb + 64 + prow;
        if(pkc < 16 && slot < min(sb+128, sEnd))
          nv = __builtin_nontemporal_load((const u32x4*)(ebC + (size_t)slot*16 + pkc));
      }

      { // stage-1 MFMA -> hid1 transposed into sHT[col][slot]
        bf16x8 a[4];
#pragma unroll
        for(int fi=0;fi<4;fi++)
          a[fi] = *(const bf16x8*)((const char*)sEBc + swzb(fi*16+lc, lg*16, 64));
#pragma unroll
        for(int fj=0;fj<4;fj++){
          bf16x8 b = *(const bf16x8*)(w1T + (size_t)(w*4+fj)*512 + l*8);
          int col = w*64 + fj*16 + lc;
          float bias = b1e[col];
#pragma unroll
          for(int fi=0;fi<4;fi++){
            f32x4 s1 = mfma16(a[fi], b, z4);
#pragma unroll
            for(int r=0;r<4;r++){
              int slot = fi*16 + lg*4 + r;
              float v = s1[r] + bias;
              v = v > 0.f ? v : 0.f;
              *(unsigned short*)((char*)sHT + swzb(col, slot*2, 128)) = f2bf(v);
            }
          }
        }
      }

      // sel rows: thread t<64 owns atom-local row t (race-free full-row write)
      if(t < 64){
        int lo = max(sOff[t], sb) - sb;
        int hi = min(sOff[t+1], se) - sb;
#pragma unroll
        for(int g=0; g<8; g++){
          union { u32x4 v; unsigned short us[8]; } pk;
#pragma unroll
          for(int j=0;j<8;j++){
            int s = g*8 + j;
            pk.us[j] = (s >= lo && s < hi) ? (unsigned short)0x3F80 : (unsigned short)0;
          }
          *(u32x4*)((char*)sSel + swzb(t, g*16, 128)) = pk.v;
        }
      }

      if(hasNext)
        *(u32x4*)((char*)sEBn + swzb(prow, pkc*2, 64)) = nv;
      __syncthreads();                 // sHT + sSel ready

      // reduce: hacc += sel @ hid1
#pragma unroll
      for(int ks=0; ks<2; ks++){
        bf16x8 as[4], bh[4];
#pragma unroll
        for(int fi=0;fi<4;fi++)
          as[fi] = *(const bf16x8*)((const char*)sSel + swzb(fi*16+lc, (ks*32+lg*8)*2, 128));
#pragma unroll
        for(int fj=0;fj<4;fj++)
          bh[fj] = *(const bf16x8*)((const char*)sHT + swzb(w*64+fj*16+lc, (ks*32+lg*8)*2, 128));
#pragma unroll
        for(int fi=0;fi<4;fi++)
#pragma unroll
          for(int fj=0;fj<4;fj++)
            hacc[fi][fj] = mfma16(as[fi], bh[fj], hacc[fi][fj]);
      }
      cur ^= 1;
    }
  }
  __syncthreads();                     // last reduce done; sHT region becomes sH

  // write hidsum (bf16) into sH row-major [atom][col]
#pragma unroll
  for(int fj=0;fj<4;fj++){
    int col = w*64 + fj*16 + lc;
#pragma unroll
    for(int fi=0;fi<4;fi++)
#pragma unroll
      for(int r=0;r<4;r++){
        int row = fi*16 + lg*4 + r;
        *(unsigned short*)((char*)sH + swzb(row, col*2, 512)) = f2bf(hacc[fi][fj][r]);
      }
  }
  __syncthreads();

  // ---- Phase B1: aggr = bf16( hidsum@W2 + deg*b2e + hsum ) ----
  {
    f32x4 zacc[4][4];
#pragma unroll
    for(int fi=0;fi<4;fi++)
#pragma unroll
      for(int fj=0;fj<4;fj++) zacc[fi][fj] = z4;
    for(int k0=0;k0<256;k0+=32){
      bf16x8 a[4], b[4];
#pragma unroll
      for(int fi=0;fi<4;fi++)
        a[fi] = *(const bf16x8*)((const char*)sH + swzb(fi*16+lc, (k0+lg*8)*2, 512));
#pragma unroll
      for(int fj=0;fj<4;fj++)
        b[fj] = *(const bf16x8*)(w2T + ((size_t)(w*4+fj)*8 + (k0>>5))*512 + l*8);
#pragma unroll
      for(int fi=0;fi<4;fi++)
#pragma unroll
        for(int fj=0;fj<4;fj++)
          zacc[fi][fj] = mfma16(a[fi], b[fj], zacc[fi][fj]);
    }
    __syncthreads();   // done reading hidsum from sH

    // stage hsum tile into sH
    for(int i=t; i<2048; i+=256){
      int row = i >> 5, q = i & 31;
      int gr = m0 + row;
      u32x4 v = {0,0,0,0};
      if(gr < N) v = __builtin_nontemporal_load(((const u32x4*)(hsum + (size_t)gr*HID)) + q);
      *(u32x4*)((char*)sH + swzb(row, q*16, 512)) = v;
    }
    __syncthreads();

    // combine in LDS: sH = bf16( zacc + deg*b2e + hsum )
#pragma unroll
    for(int fj=0;fj<4;fj++){
      int col = w*64 + fj*16 + lc;
      float b2c = b2e[col];
#pragma unroll
      for(int fi=0;fi<4;fi++)
#pragma unroll
        for(int r=0;r<4;r++){
          int row = fi*16 + lg*4 + r;
          unsigned short* p = (unsigned short*)((char*)sH + swzb(row, col*2, 512));
          float v = zacc[fi][fj][r] + (float)sDeg[row]*b2c + bf2f(*p);
          *p = f2bf(v);
        }
    }
  }
  __syncthreads();

  // ---- Phase B2: node MLP from sH (aggr) ----
  f32x4 nacc[4][4];
#pragma unroll
  for(int fi=0;fi<4;fi++)
#pragma unroll
    for(int fj=0;fj<4;fj++) nacc[fi][fj] = z4;

  for(int c=0;c<4;c++){
    f32x4 h1[4][2];
#pragma unroll
    for(int fi=0;fi<4;fi++){ h1[fi][0] = z4; h1[fi][1] = z4; }
    for(int k0=0;k0<256;k0+=32){
      bf16x8 a[4];
#pragma unroll
      for(int fi=0;fi<4;fi++)
        a[fi] = *(const bf16x8*)((const char*)sH + swzb(fi*16+lc, (k0+lg*8)*2, 512));
#pragma unroll
      for(int fj=0;fj<2;fj++){
        bf16x8 b = *(const bf16x8*)(m1T + ((size_t)(c*8 + w*2 + fj)*8 + (k0>>5))*512 + l*8);
#pragma unroll
        for(int fi=0;fi<4;fi++)
          h1[fi][fj] = mfma16(a[fi], b, h1[fi][fj]);
      }
    }
    __syncthreads();
#pragma unroll
    for(int fj=0;fj<2;fj++){
      int col  = c*128 + w*32 + fj*16 + lc;
      int lcol = w*32 + fj*16 + lc;
      float bias = b1n[col];
#pragma unroll
      for(int fi=0;fi<4;fi++)
#pragma unroll
        for(int r=0;r<4;r++){
          int row = fi*16 + lg*4 + r;
          float v = h1[fi][fj][r] + bias;
          v = v > 0.f ? v : 0.f;
          *(unsigned short*)((char*)sHD + swzb(row, lcol*2, 256)) = f2bf(v);
        }
    }
    __syncthreads();
    for(int k0=0;k0<128;k0+=32){
      bf16x8 a[4], b[4];
#pragma unroll
      for(int fi=0;fi<4;fi++)
        a[fi] = *(const bf16x8*)((const char*)sHD + swzb(fi*16+lc, (k0+lg*8)*2, 256));
#pragma unroll
      for(int fj=0;fj<4;fj++)
        b[fj] = *(const bf16x8*)(m2T + ((size_t)(w*4+fj)*16 + c*4 + (k0>>5))*512 + l*8);
#pragma unroll
      for(int fi=0;fi<4;fi++)
#pragma unroll
        for(int fj=0;fj<4;fj++)
          nacc[fi][fj] = mfma16(a[fi], b[fj], nacc[fi][fj]);
    }
  }

  // BN stats
  float bb[4];
#pragma unroll
  for(int fj=0;fj<4;fj++){
    int col = w*64 + fj*16 + lc;
    bb[fj] = b2n[col];
    float s1 = 0.f, s2 = 0.f;
#pragma unroll
    for(int fi=0;fi<4;fi++)
#pragma unroll
      for(int r=0;r<4;r++){
        int gr = m0 + fi*16 + lg*4 + r;
        float v = nacc[fi][fj][r] + bb[fj];
        if(gr < N){ s1 += v; s2 += v*v; }
      }
    s1 += __shfl_xor(s1, 16, 64); s1 += __shfl_xor(s1, 32, 64);
    s2 += __shfl_xor(s2, 16, 64); s2 += __shfl_xor(s2, 32, 64);
    if(lg == 0){
      atomicAdd(&stats[col],       s1);
      atomicAdd(&stats[HID + col], s2);
    }
  }

  // z write restaged through LDS
  float* sZF = (float*)SM;   // [32][260] f32 = 33280 B
#pragma unroll
  for(int half=0; half<2; half++){
    __syncthreads();
#pragma unroll
    for(int fj=0;fj<4;fj++){
      int col = w*64 + fj*16 + lc;
#pragma unroll
      for(int fp=0;fp<2;fp++){
        int fi = half*2 + fp;
#pragma unroll
        for(int r=0;r<4;r++){
          int row32 = fp*16 + lg*4 + r;
          sZF[row32*260 + col] = nacc[fi][fj][r] + bb[fj];
        }
      }
    }
    __syncthreads();
    for(int i=t; i<2048; i+=256){
      int row = i >> 6, seg = i & 63;
      int gr = m0 + half*32 + row;
      if(gr < N){
        u32x4 v = *(const u32x4*)(sZF + row*260 + seg*4);
        __builtin_nontemporal_store(v, (u32x4*)(z + (size_t)gr*HID + seg*4));
      }
    }
  }
}

__global__ void stats_fin(const float* __restrict__ stats, float* __restrict__ musig, float invN){
  int c = threadIdx.x;
  float mu  = stats[c] * invN;
  float var = stats[HID + c] * invN - mu*mu;
  musig[c]       = mu;
  musig[HID + c] = rsqrtf(var + BN_EPS);
}

__global__ void final_bn(float* __restrict__ out, const float* __restrict__ musig,
                         const float* __restrict__ gamma, const float* __restrict__ beta,
                         long total4){
  for(long i = (long)blockIdx.x*blockDim.x + threadIdx.x; i < total4; i += (long)gridDim.x*blockDim.x){
    int c0 = ((int)(i & 63)) << 2;
    float4 v = ((const float4*)out)[i];
    float o[4] = {v.x, v.y, v.z, v.w};
#pragma unroll
    for(int c=0;c<4;c++)
      o[c] = gamma[c0+c]*(o[c] - musig[c0+c])*musig[256+c0+c] + beta[c0+c];
    float4 ov = {o[0], o[1], o[2], o[3]};
    ((float4*)out)[i] = ov;
  }
}

// ---------------- host ----------------
// Workspace ~190 MB. Intermediate z lives in d_out.

extern "C" void kernel_launch(void* const* d_in, const int* in_sizes, int n_in,
                              void* d_out, int out_size, void* d_ws, size_t ws_size,
                              hipStream_t stream)
{
  const float* f_atoms = (const float*)d_in[0];
  const float* f_bonds = (const float*)d_in[1];
  const int*   a2b     = (const int*)d_in[2];
  const int*   b2a     = (const int*)d_in[3];
  const float* w_atom  = (const float*)d_in[6];
  const float* wb_w1   = (const float*)d_in[7];
  const float* wb_b1   = (const float*)d_in[8];
  const float* wb_w2   = (const float*)d_in[9];
  const float* wb_b2   = (const float*)d_in[10];
  const float* mlp_w1  = (const float*)d_in[11];
  const float* mlp_b1  = (const float*)d_in[12];
  const float* mlp_w2  = (const float*)d_in[13];
  const float* mlp_b2  = (const float*)d_in[14];
  const float* bn_g    = (const float*)d_in[15];
  const float* bn_b    = (const float*)d_in[16];
  const int N = in_sizes[0] / AFD;
  const int E = in_sizes[3];
  float* out = (float*)d_out;
  (void)n_in; (void)out_size; (void)ws_size;

  char* ws = (char*)d_ws;
  size_t off = 0;
  auto alloc = [&](size_t bytes)->char* {
    char* p = ws + off; off += (bytes + 255) & ~(size_t)255; return p;
  };
  unsigned short* hbn   = (unsigned short*)alloc((size_t)N*HID*2);
  unsigned short* hsum  = (unsigned short*)alloc((size_t)N*HID*2);
  unsigned short* eb    = (unsigned short*)alloc((size_t)E*16*2);
  unsigned short* ebC   = (unsigned short*)alloc((size_t)E*16*2);
  int* srcC             = (int*)alloc((size_t)E*4);
  int* b2slot           = (int*)alloc((size_t)E*4);
  int* slot2b           = (int*)alloc((size_t)E*4);
  int* offsets          = (int*)alloc((size_t)(N+1)*4);
  int* offs_local       = (int*)alloc((size_t)N*4);
  int* partials         = (int*)alloc((size_t)512*4);
  int* total            = (int*)alloc((size_t)4);
  int* unc              = (int*)alloc((size_t)(1+UNC_CAP)*4);
  unsigned short* wAT   = (unsigned short*)alloc((size_t)HID*KA_PAD*2);
  unsigned short* w1T   = (unsigned short*)alloc((size_t)3*HID*KB_PAD*2);
  unsigned short* w2T   = (unsigned short*)alloc((size_t)3*HID*HID*2);
  unsigned short* m1T   = (unsigned short*)alloc((size_t)3*512*HID*2);
  unsigned short* m2T   = (unsigned short*)alloc((size_t)3*HID*512*2);
  float* sl             = (float*)alloc((size_t)3*HID*4);
  float* stats          = (float*)alloc((size_t)3*512*4);
  float* musig          = (float*)alloc((size_t)3*512*4);
  float* lo             = (float*)alloc((size_t)3*HID*4);

  hipMemsetAsync(stats,  0,    (size_t)3*512*4, stream);
  hipMemsetAsync(b2slot, 0xFF, (size_t)E*4, stream);
  hipMemsetAsync(unc,    0,    (size_t)(1+UNC_CAP)*4, stream);

  auto cdiv = [](long a, long b){ return (int)((a + b - 1)/b); };
  const int nb = cdiv(N, 256);

  count_scan<<<nb,256,0,stream>>>(a2b, offs_local, partials, N);
  scan_partials<<<1,512,0,stream>>>(partials, nb, total);
  add_base<<<512,256,0,stream>>>(offs_local, partials, total, offsets, N);
  build_slot<<<2048,256,0,stream>>>(a2b, offsets, b2slot, slot2b, N);
  pack_eb<<<2048,256,0,stream>>>(f_bonds, eb, E);
  reorder_csr<<<2048,256,0,stream>>>(slot2b, total, eb, b2a, ebC, srcC);
  build_unc<<<2048,256,0,stream>>>(b2slot, unc, E);

  pack_wfrag<<<cdiv((long)HID*KA_PAD,256),256,0,stream>>>(w_atom, wAT, AFD, KA_PAD, HID);
  for(int l=0;l<3;l++){
    pack_wfrag<<<cdiv((long)HID*KB_PAD,256),256,0,stream>>>(wb_w1 + (size_t)l*16*HID,  w1T + (size_t)l*HID*KB_PAD, 16,  KB_PAD, HID);
    pack_wfrag<<<cdiv((long)HID*HID,256),256,0,stream>>>(wb_w2 + (size_t)l*HID*HID,  w2T + (size_t)l*HID*HID,  HID, HID, HID);
    pack_wfrag<<<cdiv((long)512*HID,256),256,0,stream>>>(mlp_w1 + (size_t)l*HID*512, m1T + (size_t)l*512*HID,  HID, HID, 512);
    pack_wfrag<<<cdiv((long)HID*512,256),256,0,stream>>>(mlp_w2 + (size_t)l*512*HID, m2T + (size_t)l*HID*512,  512, 512, HID);
  }
  sl_emb_kernel<<<3,256,0,stream>>>(wb_w1, wb_b1, wb_w2, wb_b2, sl);

  atom_embed<<<cdiv(N,64),256,0,stream>>>(f_atoms, wAT, hbn, N);

  for(int l=0;l<3;l++){
    if(l > 0){
      bn_relu_pack<<<2048,256,0,stream>>>(out, musig + (size_t)(l-1)*512,
          bn_g + (size_t)(l-1)*HID, bn_b + (size_t)(l-1)*HID, hbn, (long)N*32);
    }
    leftover_mlp<<<1,256,0,stream>>>(eb, b2a, unc,
        w1T + (size_t)l*HID*KB_PAD, wb_b1 + (size_t)l*HID,
        w2T + (size_t)l*HID*HID,    wb_b2 + (size_t)l*HID,
        hbn, lo + (size_t)l*HID);
    hsum_gather<<<2048,256,0,stream>>>(offsets, srcC, hbn,
        sl + (size_t)l*HID, lo + (size_t)l*HID, hsum, N);
    layer_atom<<<cdiv(N,64),256,0,stream>>>(ebC, offsets,
        w1T + (size_t)l*HID*KB_PAD, wb_b1 + (size_t)l*HID,
        w2T + (size_t)l*HID*HID,    wb_b2 + (size_t)l*HID,
        hsum,
        m1T + (size_t)l*512*HID, mlp_b1 + (size_t)l*512,
        m2T + (size_t)l*HID*512, mlp_b2 + (size_t)l*HID,
        out, stats + (size_t)l*512, N);
    stats_fin<<<1,256,0,stream>>>(stats + (size_t)l*512, musig + (size_t)l*512, 1.0f/(float)N);
  }
  final_bn<<<2048,256,0,stream>>>(out, musig + 2*512, bn_g + 2*HID, bn_b + 2*HID, (long)N*64);
}

// Round 22
// 1139.437 us; speedup vs baseline: 2.4565x; 1.0398x over previous
//
#include <hip/hip_runtime.h>
#include <hip/hip_bf16.h>

#define HID     256
#define AFD     133
#define KA_PAD  160
#define KB_PAD  32
#define MAXNB   16
#define BN_EPS  1e-5f
#define UNC_CAP 8192

typedef __attribute__((ext_vector_type(8))) __bf16 bf16x8;
typedef __attribute__((ext_vector_type(4))) float  f32x4;
typedef unsigned int u32x4 __attribute__((ext_vector_type(4)));
typedef unsigned int u32x2 __attribute__((ext_vector_type(2)));

__device__ __forceinline__ unsigned short f2bf(float x){
  union { __hip_bfloat16 b; unsigned short u; } cv;
  cv.b = __float2bfloat16(x);
  return cv.u;
}
__device__ __forceinline__ float bf2f(unsigned short u){
  union { unsigned int i; float f; } cv;
  cv.i = ((unsigned int)u) << 16;
  return cv.f;
}

__device__ __forceinline__ unsigned swzb(int row, int kbyte, int rowStrideB){
  return (unsigned)(row*rowStrideB + kbyte) ^ (unsigned)((row & 7) << 4);
}

__device__ __forceinline__ f32x4 mfma16(bf16x8 a, bf16x8 b, f32x4 c){
  return __builtin_amdgcn_mfma_f32_16x16x32_bf16(a, b, c, 0, 0, 0);
}

// scalar index into fragment-major weight layout [col_tile][kstep][lane][8]
__device__ __forceinline__ size_t wfidx(int k, int col, int nks){
  return ((size_t)((col>>4)*nks + (k>>5))*64 + (size_t)((((k>>3)&3)<<4) + (col&15)))*8 + (k&7);
}

// ---------------- packing: all 13 weight tensors in one grid-stride kernel ----------------
// segment layout (within-segment index math identical to the old pack_wfrag):
//   [0,40960)            wAT  : Kreal=133 Kpad=160 Ncols=256, src w_atom
//   [.., +24576)  3x8192 w1T  : Kreal=16  Kpad=32  Ncols=256, src wb_w1 (+l*16*256)
//   [.., +196608) 3x65536 w2T : Kreal=256 Kpad=256 Ncols=256, src wb_w2 (+l*65536)
//   [.., +393216) 3x131072 m1T: Kreal=256 Kpad=256 Ncols=512, src mlp_w1 (+l*131072)
//   [.., +393216) 3x131072 m2T: Kreal=512 Kpad=512 Ncols=256, src mlp_w2 (+l*131072)

__global__ void pack_all(const float* __restrict__ w_atom,
                         const float* __restrict__ wb_w1,
                         const float* __restrict__ wb_w2,
                         const float* __restrict__ mlp_w1,
                         const float* __restrict__ mlp_w2,
                         unsigned short* __restrict__ wAT,
                         unsigned short* __restrict__ w1T,
                         unsigned short* __restrict__ w2T,
                         unsigned short* __restrict__ m1T,
                         unsigned short* __restrict__ m2T){
  const int TOT = 40960 + 24576 + 196608 + 393216 + 393216;   // 1048576
  for(int idx = blockIdx.x*blockDim.x + threadIdx.x; idx < TOT; idx += gridDim.x*blockDim.x){
    const float* W; unsigned short* D; int Kreal, Kpad, Ncols, li;
    int i = idx;
    if(i < 40960){
      W = w_atom; D = wAT; Kreal = AFD; Kpad = KA_PAD; Ncols = HID; li = i;
    } else if((i -= 40960) < 24576){
      int l = i / 8192;  li = i % 8192;
      W = wb_w1 + (size_t)l*16*HID;    D = w1T + (size_t)l*8192;
      Kreal = 16;  Kpad = KB_PAD; Ncols = HID;
    } else if((i -= 24576) < 196608){
      int l = i / 65536; li = i % 65536;
      W = wb_w2 + (size_t)l*65536;     D = w2T + (size_t)l*65536;
      Kreal = HID; Kpad = HID;   Ncols = HID;
    } else if((i -= 196608) < 393216){
      int l = i / 131072; li = i % 131072;
      W = mlp_w1 + (size_t)l*131072;   D = m1T + (size_t)l*131072;
      Kreal = HID; Kpad = HID;   Ncols = 512;
    } else {
      i -= 393216;
      int l = i / 131072; li = i % 131072;
      W = mlp_w2 + (size_t)l*131072;   D = m2T + (size_t)l*131072;
      Kreal = 512; Kpad = 512;   Ncols = HID;
    }
    int nks  = Kpad >> 5;
    int j    = li & 7;
    int lane = (li >> 3) & 63;
    int rest = li >> 9;
    int ks   = rest % nks;
    int cj   = rest / nks;
    int k    = ks*32 + ((lane>>4)<<3) + j;
    int col  = cj*16 + (lane & 15);
    float v = (k < Kreal) ? W[(size_t)k*Ncols + col] : 0.f;
    D[li] = f2bf(v);
  }
}

// ---------------- CSR slot machinery ----------------

__global__ void count_scan(const int* __restrict__ a2b, int* __restrict__ offs_local,
                           int* __restrict__ partials, int N){
  __shared__ int s[256];
  int t = threadIdx.x;
  int a = blockIdx.x*256 + t;
  int c = 0;
  if(a < N){
    const int* ab = a2b + (size_t)a*MAXNB;
#pragma unroll
    for(int j4=0;j4<4;j4++){
      int4 iv = *(const int4*)(ab + j4*4);
      c += (iv.x>0) + (iv.y>0) + (iv.z>0) + (iv.w>0);
    }
  }
  s[t] = c;
  __syncthreads();
  for(int off=1; off<256; off<<=1){
    int u = (t>=off) ? s[t-off] : 0;
    __syncthreads();
    s[t] += u;
    __syncthreads();
  }
  if(a < N) offs_local[a] = s[t] - c;
  if(t == 255) partials[blockIdx.x] = s[255];
}

__global__ void scan_partials(int* __restrict__ partials, int nb, int* __restrict__ total){
  __shared__ int s[512];
  int t = threadIdx.x;
  int v = (t < nb) ? partials[t] : 0;
  s[t] = v;
  __syncthreads();
  for(int off=1; off<512; off<<=1){
    int u = (t>=off) ? s[t-off] : 0;
    __syncthreads();
    s[t] += u;
    __syncthreads();
  }
  if(t < nb) partials[t] = s[t] - v;
  if(t == 511) *total = s[511];
}

__global__ void add_base(const int* __restrict__ offs_local, const int* __restrict__ partials,
                         const int* __restrict__ total, int* __restrict__ offsets, int N){
  for(int i = blockIdx.x*blockDim.x + threadIdx.x; i < N; i += gridDim.x*blockDim.x)
    offsets[i] = offs_local[i] + partials[i >> 8];
  if(blockIdx.x == 0 && threadIdx.x == 0) offsets[N] = *total;
}

__global__ void build_slot(const int* __restrict__ a2b, const int* __restrict__ offsets,
                           int* __restrict__ b2slot, int* __restrict__ slot2b, int N){
  int totalIdx = N*MAXNB;
  for(int idx = blockIdx.x*blockDim.x + threadIdx.x; idx < totalIdx; idx += gridDim.x*blockDim.x){
    int b = a2b[idx];
    if(b > 0){
      int slot = offsets[idx >> 4] + (idx & 15);
      b2slot[b] = slot;
      slot2b[slot] = b;
    }
  }
}

// ebC[slot] = bf16(f_bonds[slot2b[slot]]) (16th col = 0), srcC[slot] = b2a[slot2b[slot]]
// (pack_eb fused in: values bit-identical to the old eb->copy path)
__global__ void reorder_csr(const int* __restrict__ slot2b, const int* __restrict__ total,
                            const float* __restrict__ fb, const int* __restrict__ b2a,
                            unsigned short* __restrict__ ebC, int* __restrict__ srcC){
  int tot = *total;
  for(int s = blockIdx.x*blockDim.x + threadIdx.x; s < tot; s += gridDim.x*blockDim.x){
    int b = slot2b[s];
    srcC[s] = b2a[b];
    union { uint4 v[2]; unsigned short us[16]; } pk;
#pragma unroll
    for(int k=0;k<15;k++) pk.us[k] = f2bf(fb[(size_t)b*15 + k]);
    pk.us[15] = 0;
    *(uint4*)(ebC + (size_t)s*16)     = pk.v[0];
    *(uint4*)(ebC + (size_t)s*16 + 8) = pk.v[1];
  }
}

__global__ void build_unc(const int* __restrict__ b2slot, int* __restrict__ unc, int E){
  for(int e = blockIdx.x*blockDim.x + threadIdx.x; e < E; e += gridDim.x*blockDim.x){
    if(b2slot[e] < 0){
      int p = atomicAdd(&unc[0], 1);
      if(p < UNC_CAP) unc[1+p] = e;
    }
  }
}

// ---------------- misc small kernels ----------------

__global__ void sl_emb_kernel(const float* __restrict__ w1, const float* __restrict__ b1,
                              const float* __restrict__ w2, const float* __restrict__ b2,
                              float* __restrict__ sl){
  int l = blockIdx.x, t = threadIdx.x;
  __shared__ float hid[HID];
  float hv = w1[((size_t)l*16 + 15)*HID + t] + b1[(size_t)l*HID + t];
  hid[t] = hv > 0.f ? hv : 0.f;
  __syncthreads();
  const float* W2 = w2 + (size_t)l*HID*HID;
  float acc = b2[(size_t)l*HID + t];
  for(int k=0;k<HID;k++) acc += hid[k] * W2[(size_t)k*HID + t];
  sl[(size_t)l*HID + t] = acc;
}

// lo = sum over uncovered bonds of (bf16(e_emb+b2) + hbn[b2a]) ; single block
// reads f_bonds directly with the same bf16 rounding the packed path used
__global__ void leftover_mlp(const float* __restrict__ fb, const int* __restrict__ b2a,
                             const int* __restrict__ unc,
                             const unsigned short* __restrict__ w1T, const float* __restrict__ b1,
                             const unsigned short* __restrict__ w2T, const float* __restrict__ b2,
                             const unsigned short* __restrict__ hbn, float* __restrict__ lo){
  __shared__ float sEB16[16];
  __shared__ float sh1[HID];
  int t = threadIdx.x;
  int nU = unc[0]; if(nU > UNC_CAP) nU = UNC_CAP;
  float acc = 0.f;
  for(int u=0; u<nU; u++){
    int e = unc[1+u];
    if(t < 16) sEB16[t] = (t < 15) ? bf2f(f2bf(fb[(size_t)e*15 + t])) : 0.f;
    __syncthreads();
    float h = b1[t];
#pragma unroll
    for(int k=0;k<16;k++) h += sEB16[k] * bf2f(w1T[wfidx(k, t, KB_PAD>>5)]);
    h = h > 0.f ? h : 0.f;
    sh1[t] = bf2f(f2bf(h));
    __syncthreads();
    float v = b2[t];
    for(int k=0;k<HID;k++) v += sh1[k] * bf2f(w2T[wfidx(k, t, HID>>5)]);
    int src = b2a[e];
    acc += bf2f(f2bf(v)) + bf2f(hbn[(size_t)src*HID + t]);
    __syncthreads();
  }
  lo[t] = acc;
}

// hbn = bf16( BN(h) relu ) for layers >= 1
__global__ void bn_relu_pack(const float* __restrict__ h,
                             const float* __restrict__ musig, const float* __restrict__ gamma,
                             const float* __restrict__ beta,
                             unsigned short* __restrict__ hbn, long total8){
  for(long i = (long)blockIdx.x*blockDim.x + threadIdx.x; i < total8; i += (long)gridDim.x*blockDim.x){
    int c0 = ((int)(i & 31)) << 3;
    f32x4 v0 = __builtin_nontemporal_load(((const f32x4*)h) + i*2);
    f32x4 v1 = __builtin_nontemporal_load(((const f32x4*)h) + i*2 + 1);
    float o[8] = {v0[0],v0[1],v0[2],v0[3],v1[0],v1[1],v1[2],v1[3]};
#pragma unroll
    for(int c=0;c<8;c++){
      float x = gamma[c0+c]*(o[c] - musig[c0+c])*musig[256+c0+c] + beta[c0+c];
      o[c] = x > 0.f ? x : 0.f;
    }
    union { uint4 v; unsigned short us[8]; } pk;
#pragma unroll
    for(int c=0;c<8;c++) pk.us[c] = f2bf(o[c]);
    ((uint4*)hbn)[i] = pk.v;
  }
}

// ---------------- atom embed: hbn0 = bf16(f_atoms @ w_atom) ----------------

__global__ __launch_bounds__(256,2) void atom_embed(
    const float* __restrict__ fat, const unsigned short* __restrict__ wAT,
    unsigned short* __restrict__ hbn, int N)
{
  __shared__ alignas(16) char SM[32768];
  unsigned short* sA = (unsigned short*)SM;
  const int t = threadIdx.x;
  const int m0 = blockIdx.x*64;
  for(int i=t; i<64*KA_PAD; i+=256){
    int row = i / KA_PAD;
    int k   = i - row*KA_PAD;
    int gr  = m0 + row;
    float v = (gr < N && k < AFD) ? fat[(size_t)gr*AFD + k] : 0.f;
    *(unsigned short*)((char*)sA + swzb(row, k*2, KA_PAD*2)) = f2bf(v);
  }
  __syncthreads();
  const int w = t>>6, l = t&63, lg = l>>4, lc = l&15;
  const f32x4 z4 = {0.f,0.f,0.f,0.f};
  f32x4 acc[4][4];
#pragma unroll
  for(int fi=0;fi<4;fi++)
#pragma unroll
    for(int fj=0;fj<4;fj++) acc[fi][fj] = z4;
  for(int k0=0;k0<KA_PAD;k0+=32){
    bf16x8 a[4], b[4];
#pragma unroll
    for(int fi=0;fi<4;fi++)
      a[fi] = *(const bf16x8*)((const char*)sA + swzb(fi*16+lc, (k0+lg*8)*2, KA_PAD*2));
#pragma unroll
    for(int fj=0;fj<4;fj++)
      b[fj] = *(const bf16x8*)(wAT + ((size_t)(w*4+fj)*5 + (k0>>5))*512 + l*8);
#pragma unroll
    for(int fi=0;fi<4;fi++)
#pragma unroll
      for(int fj=0;fj<4;fj++)
        acc[fi][fj] = mfma16(a[fi], b[fj], acc[fi][fj]);
  }
  __syncthreads();
#pragma unroll
  for(int fj=0;fj<4;fj++){
    int col = w*64 + fj*16 + lc;
#pragma unroll
    for(int fi=0;fi<4;fi++)
#pragma unroll
      for(int r=0;r<4;r++){
        int row = fi*16 + lg*4 + r;
        *(unsigned short*)(SM + swzb(row, col*2, 512)) = f2bf(acc[fi][fj][r]);
      }
  }
  __syncthreads();
  for(int c=t; c<2048; c+=256){
    int row = c >> 5, q = c & 31;
    int gr = m0 + row;
    if(gr < N){
      uint4 v = *(const uint4*)(SM + swzb(row, q*16, 512));
      ((uint4*)(hbn + (size_t)gr*HID))[q] = v;
    }
  }
}

// ---------------- hsum_gather: hsum[a] = bf16( hbn[a] + sl (+lo) + sum hbn[srcC[slot]] ) ----------------

__global__ __launch_bounds__(256,8) void hsum_gather(
    const int* __restrict__ offsets, const int* __restrict__ srcC,
    const unsigned short* __restrict__ hbn,
    const float* __restrict__ sl, const float* __restrict__ lo,
    unsigned short* __restrict__ hsum, int N)
{
  const int lane = threadIdx.x & 63;
  const int gw   = (blockIdx.x*blockDim.x + threadIdx.x) >> 6;
  const int nw   = (gridDim.x*blockDim.x) >> 6;
  const int c0   = lane*4;

  for(int a = gw; a < N; a += nw){
    float acc[4];
    {
      union { uint2 v; unsigned short us[4]; } hv;
      hv.v = *(const uint2*)(hbn + (size_t)a*HID + c0);
#pragma unroll
      for(int x=0;x<4;x++) acc[x] = bf2f(hv.us[x]);
    }
#pragma unroll
    for(int x=0;x<4;x++) acc[x] += sl[c0+x];
    if(a == 0){
#pragma unroll
      for(int x=0;x<4;x++) acc[x] += lo[c0+x];
    }
    int s    = offsets[a];
    int send = offsets[a+1];
    for(; s+1 < send; s += 2){
      int src0 = srcC[s], src1 = srcC[s+1];
      union { uint2 v; unsigned short us[4]; } g0v, g1v;
      g0v.v = *(const uint2*)(hbn + (size_t)src0*HID + c0);
      g1v.v = *(const uint2*)(hbn + (size_t)src1*HID + c0);
#pragma unroll
      for(int x=0;x<4;x++) acc[x] += bf2f(g0v.us[x]) + bf2f(g1v.us[x]);
    }
    if(s < send){
      int src0 = srcC[s];
      union { uint2 v; unsigned short us[4]; } gv;
      gv.v = *(const uint2*)(hbn + (size_t)src0*HID + c0);
#pragma unroll
      for(int x=0;x<4;x++) acc[x] += bf2f(gv.us[x]);
    }
    union { u32x2 v; unsigned short us[4]; } pk;
#pragma unroll
    for(int x=0;x<4;x++) pk.us[x] = f2bf(acc[x]);
    __builtin_nontemporal_store(pk.v, (u32x2*)(hsum + (size_t)a*HID + c0));
  }
}

// ---------------- layer_atom: fused, MFMA-based segmented reduce ----------------
// LB(256,2) — the ONLY working register budget point (proven R15-R19):
//   no LB        -> compiler targets 64 VGPR -> catastrophic spill (R19)
//   LB(256,3)    -> 84 VGPR cap              -> spill (~200MB/dispatch, R12-R14)
//   LB(256,2)    -> 128 cap, 120 used        -> clean (WRITE == z exactly)
// Phase A: hidsum = sel @ relu(ebC@W1+b1)  (MFMA sel-reduce, ebC dbuf)
// Phase B1: aggr = bf16( hidsum@W2 + deg*b2e + hsum )
// Phase B2: z = mlp(aggr) + BN stats + coalesced z write

__global__ __launch_bounds__(256,2) void layer_atom(
    const unsigned short* __restrict__ ebC, const int* __restrict__ offsets,
    const unsigned short* __restrict__ w1T, const float* __restrict__ b1e,
    const unsigned short* __restrict__ w2T, const float* __restrict__ b2e,
    const unsigned short* __restrict__ hsum,
    const unsigned short* __restrict__ m1T, const float* __restrict__ b1n,
    const unsigned short* __restrict__ m2T, const float* __restrict__ b2n,
    float* __restrict__ z, float* __restrict__ stats, int N)
{
  __shared__ alignas(16) char SM[53248];
  // phase A: sEB0 @0 (4KB) | sHT @4096 (32KB: [256 col][64 slot] bf16 swz128)
  //          sSel @36864 (8KB: [64 atom][64 slot] bf16 swz128) | sEB1 @45056 (4KB)
  // phase B: sH @4096 (hidsum/aggr, row-major swz512) | sHD @36864 (16KB)
  // z-write: sZF @0 (33280B)
  unsigned short* sEB0 = (unsigned short*)SM;
  unsigned short* sHT  = (unsigned short*)(SM + 4096);
  unsigned short* sH   = (unsigned short*)(SM + 4096);
  unsigned short* sSel = (unsigned short*)(SM + 36864);
  unsigned short* sHD  = (unsigned short*)(SM + 36864);
  unsigned short* sEB1 = (unsigned short*)(SM + 45056);
  __shared__ int sOff[65];
  __shared__ int sDeg[64];
  const int t  = threadIdx.x;
  const int m0 = blockIdx.x*64;

  if(t < 65) sOff[t] = offsets[min(m0 + t, N)];
  __syncthreads();
  const int sBeg = sOff[0], sEnd = sOff[64];
  if(t < 64) sDeg[t] = sOff[t+1] - sOff[t];

  const int w = t>>6, l = t&63, lg = l>>4, lc = l&15;
  const f32x4 z4 = {0.f,0.f,0.f,0.f};

  // ---- Phase A: hidsum via sel@hid1, accumulated in MFMA C regs ----
  f32x4 hacc[4][4];
#pragma unroll
  for(int fi=0;fi<4;fi++)
#pragma unroll
    for(int fj=0;fj<4;fj++) hacc[fi][fj] = z4;

  {
    const int prow = t >> 2;
    const int pkc  = (t & 3) << 3;

    // prologue: stage first tile into sEB0
    {
      int slot = sBeg + prow;
      u32x4 val = {0,0,0,0};
      if(pkc < 16 && slot < min(sBeg+64, sEnd))
        val = __builtin_nontemporal_load((const u32x4*)(ebC + (size_t)slot*16 + pkc));
      *(u32x4*)((char*)sEB0 + swzb(prow, pkc*2, 64)) = val;
    }

    int cur = 0;
    for(int sb = sBeg; sb < sEnd; sb += 64){
      const int se = min(sb + 64, sEnd);
      __syncthreads();                 // sEB[cur] visible; sHT/sSel free (prev reduce done)
      unsigned short* sEBc = cur ? sEB1 : sEB0;
      unsigned short* sEBn = cur ? sEB0 : sEB1;

      const bool hasNext = (sb + 64 < sEnd);
      u32x4 nv = {0,0,0,0};
      if(hasNext){
        int slot = sb + 64 + prow;
        if(pkc < 16 && slot < min(sb+128, sEnd))
          nv = __builtin_nontemporal_load((const u32x4*)(ebC + (size_t)slot*16 + pkc));
      }

      { // stage-1 MFMA -> hid1 transposed into sHT[col][slot]
        bf16x8 a[4];
#pragma unroll
        for(int fi=0;fi<4;fi++)
          a[fi] = *(const bf16x8*)((const char*)sEBc + swzb(fi*16+lc, lg*16, 64));
#pragma unroll
        for(int fj=0;fj<4;fj++){
          bf16x8 b = *(const bf16x8*)(w1T + (size_t)(w*4+fj)*512 + l*8);
          int col = w*64 + fj*16 + lc;
          float bias = b1e[col];
#pragma unroll
          for(int fi=0;fi<4;fi++){
            f32x4 s1 = mfma16(a[fi], b, z4);
#pragma unroll
            for(int r=0;r<4;r++){
              int slot = fi*16 + lg*4 + r;
              float v = s1[r] + bias;
              v = v > 0.f ? v : 0.f;
              *(unsigned short*)((char*)sHT + swzb(col, slot*2, 128)) = f2bf(v);
            }
          }
        }
      }

      // sel rows: thread t<64 owns atom-local row t (race-free full-row write)
      if(t < 64){
        int lo = max(sOff[t], sb) - sb;
        int hi = min(sOff[t+1], se) - sb;
#pragma unroll
        for(int g=0; g<8; g++){
          union { u32x4 v; unsigned short us[8]; } pk;
#pragma unroll
          for(int j=0;j<8;j++){
            int s = g*8 + j;
            pk.us[j] = (s >= lo && s < hi) ? (unsigned short)0x3F80 : (unsigned short)0;
          }
          *(u32x4*)((char*)sSel + swzb(t, g*16, 128)) = pk.v;
        }
      }

      if(hasNext)
        *(u32x4*)((char*)sEBn + swzb(prow, pkc*2, 64)) = nv;
      __syncthreads();                 // sHT + sSel ready

      // reduce: hacc += sel @ hid1
#pragma unroll
      for(int ks=0; ks<2; ks++){
        bf16x8 as[4], bh[4];
#pragma unroll
        for(int fi=0;fi<4;fi++)
          as[fi] = *(const bf16x8*)((const char*)sSel + swzb(fi*16+lc, (ks*32+lg*8)*2, 128));
#pragma unroll
        for(int fj=0;fj<4;fj++)
          bh[fj] = *(const bf16x8*)((const char*)sHT + swzb(w*64+fj*16+lc, (ks*32+lg*8)*2, 128));
#pragma unroll
        for(int fi=0;fi<4;fi++)
#pragma unroll
          for(int fj=0;fj<4;fj++)
            hacc[fi][fj] = mfma16(as[fi], bh[fj], hacc[fi][fj]);
      }
      cur ^= 1;
    }
  }
  __syncthreads();                     // last reduce done; sHT region becomes sH

  // write hidsum (bf16) into sH row-major [atom][col]
#pragma unroll
  for(int fj=0;fj<4;fj++){
    int col = w*64 + fj*16 + lc;
#pragma unroll
    for(int fi=0;fi<4;fi++)
#pragma unroll
      for(int r=0;r<4;r++){
        int row = fi*16 + lg*4 + r;
        *(unsigned short*)((char*)sH + swzb(row, col*2, 512)) = f2bf(hacc[fi][fj][r]);
      }
  }
  __syncthreads();

  // ---- Phase B1: aggr = bf16( hidsum@W2 + deg*b2e + hsum ) ----
  {
    f32x4 zacc[4][4];
#pragma unroll
    for(int fi=0;fi<4;fi++)
#pragma unroll
      for(int fj=0;fj<4;fj++) zacc[fi][fj] = z4;
    for(int k0=0;k0<256;k0+=32){
      bf16x8 a[4], b[4];
#pragma unroll
      for(int fi=0;fi<4;fi++)
        a[fi] = *(const bf16x8*)((const char*)sH + swzb(fi*16+lc, (k0+lg*8)*2, 512));
#pragma unroll
      for(int fj=0;fj<4;fj++)
        b[fj] = *(const bf16x8*)(w2T + ((size_t)(w*4+fj)*8 + (k0>>5))*512 + l*8);
#pragma unroll
      for(int fi=0;fi<4;fi++)
#pragma unroll
        for(int fj=0;fj<4;fj++)
          zacc[fi][fj] = mfma16(a[fi], b[fj], zacc[fi][fj]);
    }
    __syncthreads();   // done reading hidsum from sH

    // stage hsum tile into sH
    for(int i=t; i<2048; i+=256){
      int row = i >> 5, q = i & 31;
      int gr = m0 + row;
      u32x4 v = {0,0,0,0};
      if(gr < N) v = __builtin_nontemporal_load(((const u32x4*)(hsum + (size_t)gr*HID)) + q);
      *(u32x4*)((char*)sH + swzb(row, q*16, 512)) = v;
    }
    __syncthreads();

    // combine in LDS: sH = bf16( zacc + deg*b2e + hsum )
#pragma unroll
    for(int fj=0;fj<4;fj++){
      int col = w*64 + fj*16 + lc;
      float b2c = b2e[col];
#pragma unroll
      for(int fi=0;fi<4;fi++)
#pragma unroll
        for(int r=0;r<4;r++){
          int row = fi*16 + lg*4 + r;
          unsigned short* p = (unsigned short*)((char*)sH + swzb(row, col*2, 512));
          float v = zacc[fi][fj][r] + (float)sDeg[row]*b2c + bf2f(*p);
          *p = f2bf(v);
        }
    }
  }
  __syncthreads();

  // ---- Phase B2: node MLP from sH (aggr) ----
  f32x4 nacc[4][4];
#pragma unroll
  for(int fi=0;fi<4;fi++)
#pragma unroll
    for(int fj=0;fj<4;fj++) nacc[fi][fj] = z4;

  for(int c=0;c<4;c++){
    f32x4 h1[4][2];
#pragma unroll
    for(int fi=0;fi<4;fi++){ h1[fi][0] = z4; h1[fi][1] = z4; }
    for(int k0=0;k0<256;k0+=32){
      bf16x8 a[4];
#pragma unroll
      for(int fi=0;fi<4;fi++)
        a[fi] = *(const bf16x8*)((const char*)sH + swzb(fi*16+lc, (k0+lg*8)*2, 512));
#pragma unroll
      for(int fj=0;fj<2;fj++){
        bf16x8 b = *(const bf16x8*)(m1T + ((size_t)(c*8 + w*2 + fj)*8 + (k0>>5))*512 + l*8);
#pragma unroll
        for(int fi=0;fi<4;fi++)
          h1[fi][fj] = mfma16(a[fi], b, h1[fi][fj]);
      }
    }
    __syncthreads();
#pragma unroll
    for(int fj=0;fj<2;fj++){
      int col  = c*128 + w*32 + fj*16 + lc;
      int lcol = w*32 + fj*16 + lc;
      float bias = b1n[col];
#pragma unroll
      for(int fi=0;fi<4;fi++)
#pragma unroll
        for(int r=0;r<4;r++){
          int row = fi*16 + lg*4 + r;
          float v = h1[fi][fj][r] + bias;
          v = v > 0.f ? v : 0.f;
          *(unsigned short*)((char*)sHD + swzb(row, lcol*2, 256)) = f2bf(v);
        }
    }
    __syncthreads();
    for(int k0=0;k0<128;k0+=32){
      bf16x8 a[4], b[4];
#pragma unroll
      for(int fi=0;fi<4;fi++)
        a[fi] = *(const bf16x8*)((const char*)sHD + swzb(fi*16+lc, (k0+lg*8)*2, 256));
#pragma unroll
      for(int fj=0;fj<4;fj++)
        b[fj] = *(const bf16x8*)(m2T + ((size_t)(w*4+fj)*16 + c*4 + (k0>>5))*512 + l*8);
#pragma unroll
      for(int fi=0;fi<4;fi++)
#pragma unroll
        for(int fj=0;fj<4;fj++)
          nacc[fi][fj] = mfma16(a[fi], b[fj], nacc[fi][fj]);
    }
  }

  // BN stats
  float bb[4];
#pragma unroll
  for(int fj=0;fj<4;fj++){
    int col = w*64 + fj*16 + lc;
    bb[fj] = b2n[col];
    float s1 = 0.f, s2 = 0.f;
#pragma unroll
    for(int fi=0;fi<4;fi++)
#pragma unroll
      for(int r=0;r<4;r++){
        int gr = m0 + fi*16 + lg*4 + r;
        float v = nacc[fi][fj][r] + bb[fj];
        if(gr < N){ s1 += v; s2 += v*v; }
      }
    s1 += __shfl_xor(s1, 16, 64); s1 += __shfl_xor(s1, 32, 64);
    s2 += __shfl_xor(s2, 16, 64); s2 += __shfl_xor(s2, 32, 64);
    if(lg == 0){
      atomicAdd(&stats[col],       s1);
      atomicAdd(&stats[HID + col], s2);
    }
  }

  // z write restaged through LDS
  float* sZF = (float*)SM;   // [32][260] f32 = 33280 B
#pragma unroll
  for(int half=0; half<2; half++){
    __syncthreads();
#pragma unroll
    for(int fj=0;fj<4;fj++){
      int col = w*64 + fj*16 + lc;
#pragma unroll
      for(int fp=0;fp<2;fp++){
        int fi = half*2 + fp;
#pragma unroll
        for(int r=0;r<4;r++){
          int row32 = fp*16 + lg*4 + r;
          sZF[row32*260 + col] = nacc[fi][fj][r] + bb[fj];
        }
      }
    }
    __syncthreads();
    for(int i=t; i<2048; i+=256){
      int row = i >> 6, seg = i & 63;
      int gr = m0 + half*32 + row;
      if(gr < N){
        u32x4 v = *(const u32x4*)(sZF + row*260 + seg*4);
        __builtin_nontemporal_store(v, (u32x4*)(z + (size_t)gr*HID + seg*4));
      }
    }
  }
}

__global__ void stats_fin(const float* __restrict__ stats, float* __restrict__ musig, float invN){
  int c = threadIdx.x;
  float mu  = stats[c] * invN;
  float var = stats[HID + c] * invN - mu*mu;
  musig[c]       = mu;
  musig[HID + c] = rsqrtf(var + BN_EPS);
}

__global__ void final_bn(float* __restrict__ out, const float* __restrict__ musig,
                         const float* __restrict__ gamma, const float* __restrict__ beta,
                         long total4){
  for(long i = (long)blockIdx.x*blockDim.x + threadIdx.x; i < total4; i += (long)gridDim.x*blockDim.x){
    int c0 = ((int)(i & 63)) << 2;
    float4 v = ((const float4*)out)[i];
    float o[4] = {v.x, v.y, v.z, v.w};
#pragma unroll
    for(int c=0;c<4;c++)
      o[c] = gamma[c0+c]*(o[c] - musig[c0+c])*musig[256+c0+c] + beta[c0+c];
    float4 ov = {o[0], o[1], o[2], o[3]};
    ((float4*)out)[i] = ov;
  }
}

// ---------------- host ----------------
// Workspace ~177 MB (eb buffer removed). Intermediate z lives in d_out.

extern "C" void kernel_launch(void* const* d_in, const int* in_sizes, int n_in,
                              void* d_out, int out_size, void* d_ws, size_t ws_size,
                              hipStream_t stream)
{
  const float* f_atoms = (const float*)d_in[0];
  const float* f_bonds = (const float*)d_in[1];
  const int*   a2b     = (const int*)d_in[2];
  const int*   b2a     = (const int*)d_in[3];
  const float* w_atom  = (const float*)d_in[6];
  const float* wb_w1   = (const float*)d_in[7];
  const float* wb_b1   = (const float*)d_in[8];
  const float* wb_w2   = (const float*)d_in[9];
  const float* wb_b2   = (const float*)d_in[10];
  const float* mlp_w1  = (const float*)d_in[11];
  const float* mlp_b1  = (const float*)d_in[12];
  const float* mlp_w2  = (const float*)d_in[13];
  const float* mlp_b2  = (const float*)d_in[14];
  const float* bn_g    = (const float*)d_in[15];
  const float* bn_b    = (const float*)d_in[16];
  const int N = in_sizes[0] / AFD;
  const int E = in_sizes[3];
  float* out = (float*)d_out;
  (void)n_in; (void)out_size; (void)ws_size;

  char* ws = (char*)d_ws;
  size_t off = 0;
  auto alloc = [&](size_t bytes)->char* {
    char* p = ws + off; off += (bytes + 255) & ~(size_t)255; return p;
  };
  unsigned short* hbn   = (unsigned short*)alloc((size_t)N*HID*2);
  unsigned short* hsum  = (unsigned short*)alloc((size_t)N*HID*2);
  unsigned short* ebC   = (unsigned short*)alloc((size_t)E*16*2);
  int* srcC             = (int*)alloc((size_t)E*4);
  int* b2slot           = (int*)alloc((size_t)E*4);
  int* slot2b           = (int*)alloc((size_t)E*4);
  int* offsets          = (int*)alloc((size_t)(N+1)*4);
  int* offs_local       = (int*)alloc((size_t)N*4);
  int* partials         = (int*)alloc((size_t)512*4);
  int* total            = (int*)alloc((size_t)4);
  int* unc              = (int*)alloc((size_t)(1+UNC_CAP)*4);
  unsigned short* wAT   = (unsigned short*)alloc((size_t)HID*KA_PAD*2);
  unsigned short* w1T   = (unsigned short*)alloc((size_t)3*HID*KB_PAD*2);
  unsigned short* w2T   = (unsigned short*)alloc((size_t)3*HID*HID*2);
  unsigned short* m1T   = (unsigned short*)alloc((size_t)3*512*HID*2);
  unsigned short* m2T   = (unsigned short*)alloc((size_t)3*HID*512*2);
  float* sl             = (float*)alloc((size_t)3*HID*4);
  float* stats          = (float*)alloc((size_t)3*512*4);
  float* musig          = (float*)alloc((size_t)3*512*4);
  float* lo             = (float*)alloc((size_t)3*HID*4);

  hipMemsetAsync(stats,  0,    (size_t)3*512*4, stream);
  hipMemsetAsync(b2slot, 0xFF, (size_t)E*4, stream);
  hipMemsetAsync(unc,    0,    (size_t)(1+UNC_CAP)*4, stream);

  auto cdiv = [](long a, long b){ return (int)((a + b - 1)/b); };
  const int nb = cdiv(N, 256);

  count_scan<<<nb,256,0,stream>>>(a2b, offs_local, partials, N);
  scan_partials<<<1,512,0,stream>>>(partials, nb, total);
  add_base<<<512,256,0,stream>>>(offs_local, partials, total, offsets, N);
  build_slot<<<2048,256,0,stream>>>(a2b, offsets, b2slot, slot2b, N);
  reorder_csr<<<2048,256,0,stream>>>(slot2b, total, f_bonds, b2a, ebC, srcC);
  build_unc<<<2048,256,0,stream>>>(b2slot, unc, E);

  pack_all<<<2048,256,0,stream>>>(w_atom, wb_w1, wb_w2, mlp_w1, mlp_w2,
                                  wAT, w1T, w2T, m1T, m2T);
  sl_emb_kernel<<<3,256,0,stream>>>(wb_w1, wb_b1, wb_w2, wb_b2, sl);

  atom_embed<<<cdiv(N,64),256,0,stream>>>(f_atoms, wAT, hbn, N);

  for(int l=0;l<3;l++){
    if(l > 0){
      bn_relu_pack<<<2048,256,0,stream>>>(out, musig + (size_t)(l-1)*512,
          bn_g + (size_t)(l-1)*HID, bn_b + (size_t)(l-1)*HID, hbn, (long)N*32);
    }
    leftover_mlp<<<1,256,0,stream>>>(f_bonds, b2a, unc,
        w1T + (size_t)l*HID*KB_PAD, wb_b1 + (size_t)l*HID,
        w2T + (size_t)l*HID*HID,    wb_b2 + (size_t)l*HID,
        hbn, lo + (size_t)l*HID);
    hsum_gather<<<2048,256,0,stream>>>(offsets, srcC, hbn,
        sl + (size_t)l*HID, lo + (size_t)l*HID, hsum, N);
    layer_atom<<<cdiv(N,64),256,0,stream>>>(ebC, offsets,
        w1T + (size_t)l*HID*KB_PAD, wb_b1 + (size_t)l*HID,
        w2T + (size_t)l*HID*HID,    wb_b2 + (size_t)l*HID,
        hsum,
        m1T + (size_t)l*512*HID, mlp_b1 + (size_t)l*512,
        m2T + (size_t)l*HID*512, mlp_b2 + (size_t)l*HID,
        out, stats + (size_t)l*512, N);
    stats_fin<<<1,256,0,stream>>>(stats + (size_t)l*512, musig + (size_t)l*512, 1.0f/(float)N);
  }
  final_bn<<<2048,256,0,stream>>>(out, musig + 2*512, bn_g + 2*HID, bn_b + 2*HID, (long)N*64);
}

// Round 23
// 1135.942 us; speedup vs baseline: 2.4641x; 1.0031x over previous
//
#include <hip/hip_runtime.h>
#include <hip/hip_bf16.h>

#define HID     256
#define AFD     133
#define KA_PAD  160
#define KB_PAD  32
#define MAXNB   16
#define BN_EPS  1e-5f
#define UNC_CAP 8192

typedef __attribute__((ext_vector_type(8))) __bf16 bf16x8;
typedef __attribute__((ext_vector_type(4))) float  f32x4;
typedef unsigned int u32x4 __attribute__((ext_vector_type(4)));
typedef unsigned int u32x2 __attribute__((ext_vector_type(2)));

__device__ __forceinline__ unsigned short f2bf(float x){
  union { __hip_bfloat16 b; unsigned short u; } cv;
  cv.b = __float2bfloat16(x);
  return cv.u;
}
__device__ __forceinline__ float bf2f(unsigned short u){
  union { unsigned int i; float f; } cv;
  cv.i = ((unsigned int)u) << 16;
  return cv.f;
}

__device__ __forceinline__ unsigned swzb(int row, int kbyte, int rowStrideB){
  return (unsigned)(row*rowStrideB + kbyte) ^ (unsigned)((row & 7) << 4);
}

__device__ __forceinline__ f32x4 mfma16(bf16x8 a, bf16x8 b, f32x4 c){
  return __builtin_amdgcn_mfma_f32_16x16x32_bf16(a, b, c, 0, 0, 0);
}

// scalar index into fragment-major weight layout [col_tile][kstep][lane][8]
__device__ __forceinline__ size_t wfidx(int k, int col, int nks){
  return ((size_t)((col>>4)*nks + (k>>5))*64 + (size_t)((((k>>3)&3)<<4) + (col&15)))*8 + (k&7);
}

// ---------------- packing: all 13 weight tensors in one grid-stride kernel ----------------

__global__ void pack_all(const float* __restrict__ w_atom,
                         const float* __restrict__ wb_w1,
                         const float* __restrict__ wb_w2,
                         const float* __restrict__ mlp_w1,
                         const float* __restrict__ mlp_w2,
                         unsigned short* __restrict__ wAT,
                         unsigned short* __restrict__ w1T,
                         unsigned short* __restrict__ w2T,
                         unsigned short* __restrict__ m1T,
                         unsigned short* __restrict__ m2T){
  const int TOT = 40960 + 24576 + 196608 + 393216 + 393216;   // 1048576
  for(int idx = blockIdx.x*blockDim.x + threadIdx.x; idx < TOT; idx += gridDim.x*blockDim.x){
    const float* W; unsigned short* D; int Kreal, Kpad, Ncols, li;
    int i = idx;
    if(i < 40960){
      W = w_atom; D = wAT; Kreal = AFD; Kpad = KA_PAD; Ncols = HID; li = i;
    } else if((i -= 40960) < 24576){
      int l = i / 8192;  li = i % 8192;
      W = wb_w1 + (size_t)l*16*HID;    D = w1T + (size_t)l*8192;
      Kreal = 16;  Kpad = KB_PAD; Ncols = HID;
    } else if((i -= 24576) < 196608){
      int l = i / 65536; li = i % 65536;
      W = wb_w2 + (size_t)l*65536;     D = w2T + (size_t)l*65536;
      Kreal = HID; Kpad = HID;   Ncols = HID;
    } else if((i -= 196608) < 393216){
      int l = i / 131072; li = i % 131072;
      W = mlp_w1 + (size_t)l*131072;   D = m1T + (size_t)l*131072;
      Kreal = HID; Kpad = HID;   Ncols = 512;
    } else {
      i -= 393216;
      int l = i / 131072; li = i % 131072;
      W = mlp_w2 + (size_t)l*131072;   D = m2T + (size_t)l*131072;
      Kreal = 512; Kpad = 512;   Ncols = HID;
    }
    int nks  = Kpad >> 5;
    int j    = li & 7;
    int lane = (li >> 3) & 63;
    int rest = li >> 9;
    int ks   = rest % nks;
    int cj   = rest / nks;
    int k    = ks*32 + ((lane>>4)<<3) + j;
    int col  = cj*16 + (lane & 15);
    float v = (k < Kreal) ? W[(size_t)k*Ncols + col] : 0.f;
    D[li] = f2bf(v);
  }
}

// ---------------- CSR slot machinery ----------------

__global__ void count_scan(const int* __restrict__ a2b, int* __restrict__ offs_local,
                           int* __restrict__ partials, int N){
  __shared__ int s[256];
  int t = threadIdx.x;
  int a = blockIdx.x*256 + t;
  int c = 0;
  if(a < N){
    const int* ab = a2b + (size_t)a*MAXNB;
#pragma unroll
    for(int j4=0;j4<4;j4++){
      int4 iv = *(const int4*)(ab + j4*4);
      c += (iv.x>0) + (iv.y>0) + (iv.z>0) + (iv.w>0);
    }
  }
  s[t] = c;
  __syncthreads();
  for(int off=1; off<256; off<<=1){
    int u = (t>=off) ? s[t-off] : 0;
    __syncthreads();
    s[t] += u;
    __syncthreads();
  }
  if(a < N) offs_local[a] = s[t] - c;
  if(t == 255) partials[blockIdx.x] = s[255];
}

__global__ void scan_partials(int* __restrict__ partials, int nb, int* __restrict__ total){
  __shared__ int s[512];
  int t = threadIdx.x;
  int v = (t < nb) ? partials[t] : 0;
  s[t] = v;
  __syncthreads();
  for(int off=1; off<512; off<<=1){
    int u = (t>=off) ? s[t-off] : 0;
    __syncthreads();
    s[t] += u;
    __syncthreads();
  }
  if(t < nb) partials[t] = s[t] - v;
  if(t == 511) *total = s[511];
}

__global__ void add_base(const int* __restrict__ offs_local, const int* __restrict__ partials,
                         const int* __restrict__ total, int* __restrict__ offsets, int N){
  for(int i = blockIdx.x*blockDim.x + threadIdx.x; i < N; i += gridDim.x*blockDim.x)
    offsets[i] = offs_local[i] + partials[i >> 8];
  if(blockIdx.x == 0 && threadIdx.x == 0) offsets[N] = *total;
}

__global__ void build_slot(const int* __restrict__ a2b, const int* __restrict__ offsets,
                           int* __restrict__ b2slot, int* __restrict__ slot2b, int N){
  int totalIdx = N*MAXNB;
  for(int idx = blockIdx.x*blockDim.x + threadIdx.x; idx < totalIdx; idx += gridDim.x*blockDim.x){
    int b = a2b[idx];
    if(b > 0){
      int slot = offsets[idx >> 4] + (idx & 15);
      b2slot[b] = slot;
      slot2b[slot] = b;
    }
  }
}

// ebC[slot] = bf16(f_bonds[slot2b[slot]]) (16th col = 0), srcC[slot] = b2a[slot2b[slot]]
__global__ void reorder_csr(const int* __restrict__ slot2b, const int* __restrict__ total,
                            const float* __restrict__ fb, const int* __restrict__ b2a,
                            unsigned short* __restrict__ ebC, int* __restrict__ srcC){
  int tot = *total;
  for(int s = blockIdx.x*blockDim.x + threadIdx.x; s < tot; s += gridDim.x*blockDim.x){
    int b = slot2b[s];
    srcC[s] = b2a[b];
    union { uint4 v[2]; unsigned short us[16]; } pk;
#pragma unroll
    for(int k=0;k<15;k++) pk.us[k] = f2bf(fb[(size_t)b*15 + k]);
    pk.us[15] = 0;
    *(uint4*)(ebC + (size_t)s*16)     = pk.v[0];
    *(uint4*)(ebC + (size_t)s*16 + 8) = pk.v[1];
  }
}

__global__ void build_unc(const int* __restrict__ b2slot, int* __restrict__ unc, int E){
  for(int e = blockIdx.x*blockDim.x + threadIdx.x; e < E; e += gridDim.x*blockDim.x){
    if(b2slot[e] < 0){
      int p = atomicAdd(&unc[0], 1);
      if(p < UNC_CAP) unc[1+p] = e;
    }
  }
}

// ---------------- misc small kernels ----------------

__global__ void sl_emb_kernel(const float* __restrict__ w1, const float* __restrict__ b1,
                              const float* __restrict__ w2, const float* __restrict__ b2,
                              float* __restrict__ sl){
  int l = blockIdx.x, t = threadIdx.x;
  __shared__ float hid[HID];
  float hv = w1[((size_t)l*16 + 15)*HID + t] + b1[(size_t)l*HID + t];
  hid[t] = hv > 0.f ? hv : 0.f;
  __syncthreads();
  const float* W2 = w2 + (size_t)l*HID*HID;
  float acc = b2[(size_t)l*HID + t];
  for(int k=0;k<HID;k++) acc += hid[k] * W2[(size_t)k*HID + t];
  sl[(size_t)l*HID + t] = acc;
}

// lo = sum over uncovered bonds of (bf16(e_emb+b2) + hbn[b2a]) ; single block
__global__ void leftover_mlp(const float* __restrict__ fb, const int* __restrict__ b2a,
                             const int* __restrict__ unc,
                             const unsigned short* __restrict__ w1T, const float* __restrict__ b1,
                             const unsigned short* __restrict__ w2T, const float* __restrict__ b2,
                             const unsigned short* __restrict__ hbn, float* __restrict__ lo){
  __shared__ float sEB16[16];
  __shared__ float sh1[HID];
  int t = threadIdx.x;
  int nU = unc[0]; if(nU > UNC_CAP) nU = UNC_CAP;
  float acc = 0.f;
  for(int u=0; u<nU; u++){
    int e = unc[1+u];
    if(t < 16) sEB16[t] = (t < 15) ? bf2f(f2bf(fb[(size_t)e*15 + t])) : 0.f;
    __syncthreads();
    float h = b1[t];
#pragma unroll
    for(int k=0;k<16;k++) h += sEB16[k] * bf2f(w1T[wfidx(k, t, KB_PAD>>5)]);
    h = h > 0.f ? h : 0.f;
    sh1[t] = bf2f(f2bf(h));
    __syncthreads();
    float v = b2[t];
    for(int k=0;k<HID;k++) v += sh1[k] * bf2f(w2T[wfidx(k, t, HID>>5)]);
    int src = b2a[e];
    acc += bf2f(f2bf(v)) + bf2f(hbn[(size_t)src*HID + t]);
    __syncthreads();
  }
  lo[t] = acc;
}

// hbn = bf16( BN(h) relu ) for layers >= 1 ; BN params finalized inline from raw stats
// (mu = sum*invN; var = sumsq*invN - mu^2; rs = rsqrt(var+eps)) — identical FP sequence
// to the old stats_fin, so results are bit-identical.
__global__ void bn_relu_pack(const float* __restrict__ h,
                             const float* __restrict__ stats, float invN,
                             const float* __restrict__ gamma,
                             const float* __restrict__ beta,
                             unsigned short* __restrict__ hbn, long total8){
  for(long i = (long)blockIdx.x*blockDim.x + threadIdx.x; i < total8; i += (long)gridDim.x*blockDim.x){
    int c0 = ((int)(i & 31)) << 3;
    f32x4 v0 = __builtin_nontemporal_load(((const f32x4*)h) + i*2);
    f32x4 v1 = __builtin_nontemporal_load(((const f32x4*)h) + i*2 + 1);
    float o[8] = {v0[0],v0[1],v0[2],v0[3],v1[0],v1[1],v1[2],v1[3]};
#pragma unroll
    for(int c=0;c<8;c++){
      float mu  = stats[c0+c] * invN;
      float var = stats[HID + c0 + c] * invN - mu*mu;
      float rs  = rsqrtf(var + BN_EPS);
      float x = gamma[c0+c]*(o[c] - mu)*rs + beta[c0+c];
      o[c] = x > 0.f ? x : 0.f;
    }
    union { uint4 v; unsigned short us[8]; } pk;
#pragma unroll
    for(int c=0;c<8;c++) pk.us[c] = f2bf(o[c]);
    ((uint4*)hbn)[i] = pk.v;
  }
}

// ---------------- atom embed: hbn0 = bf16(f_atoms @ w_atom) ----------------

__global__ __launch_bounds__(256,2) void atom_embed(
    const float* __restrict__ fat, const unsigned short* __restrict__ wAT,
    unsigned short* __restrict__ hbn, int N)
{
  __shared__ alignas(16) char SM[32768];
  unsigned short* sA = (unsigned short*)SM;
  const int t = threadIdx.x;
  const int m0 = blockIdx.x*64;
  for(int i=t; i<64*KA_PAD; i+=256){
    int row = i / KA_PAD;
    int k   = i - row*KA_PAD;
    int gr  = m0 + row;
    float v = (gr < N && k < AFD) ? fat[(size_t)gr*AFD + k] : 0.f;
    *(unsigned short*)((char*)sA + swzb(row, k*2, KA_PAD*2)) = f2bf(v);
  }
  __syncthreads();
  const int w = t>>6, l = t&63, lg = l>>4, lc = l&15;
  const f32x4 z4 = {0.f,0.f,0.f,0.f};
  f32x4 acc[4][4];
#pragma unroll
  for(int fi=0;fi<4;fi++)
#pragma unroll
    for(int fj=0;fj<4;fj++) acc[fi][fj] = z4;
  for(int k0=0;k0<KA_PAD;k0+=32){
    bf16x8 a[4], b[4];
#pragma unroll
    for(int fi=0;fi<4;fi++)
      a[fi] = *(const bf16x8*)((const char*)sA + swzb(fi*16+lc, (k0+lg*8)*2, KA_PAD*2));
#pragma unroll
    for(int fj=0;fj<4;fj++)
      b[fj] = *(const bf16x8*)(wAT + ((size_t)(w*4+fj)*5 + (k0>>5))*512 + l*8);
#pragma unroll
    for(int fi=0;fi<4;fi++)
#pragma unroll
      for(int fj=0;fj<4;fj++)
        acc[fi][fj] = mfma16(a[fi], b[fj], acc[fi][fj]);
  }
  __syncthreads();
#pragma unroll
  for(int fj=0;fj<4;fj++){
    int col = w*64 + fj*16 + lc;
#pragma unroll
    for(int fi=0;fi<4;fi++)
#pragma unroll
      for(int r=0;r<4;r++){
        int row = fi*16 + lg*4 + r;
        *(unsigned short*)(SM + swzb(row, col*2, 512)) = f2bf(acc[fi][fj][r]);
      }
  }
  __syncthreads();
  for(int c=t; c<2048; c+=256){
    int row = c >> 5, q = c & 31;
    int gr = m0 + row;
    if(gr < N){
      uint4 v = *(const uint4*)(SM + swzb(row, q*16, 512));
      ((uint4*)(hbn + (size_t)gr*HID))[q] = v;
    }
  }
}

// ---------------- hsum_gather: hsum[a] = bf16( hbn[a] + sl (+lo) + sum hbn[srcC[slot]] ) ----------------

__global__ __launch_bounds__(256,8) void hsum_gather(
    const int* __restrict__ offsets, const int* __restrict__ srcC,
    const unsigned short* __restrict__ hbn,
    const float* __restrict__ sl, const float* __restrict__ lo,
    unsigned short* __restrict__ hsum, int N)
{
  const int lane = threadIdx.x & 63;
  const int gw   = (blockIdx.x*blockDim.x + threadIdx.x) >> 6;
  const int nw   = (gridDim.x*blockDim.x) >> 6;
  const int c0   = lane*4;

  for(int a = gw; a < N; a += nw){
    float acc[4];
    {
      union { uint2 v; unsigned short us[4]; } hv;
      hv.v = *(const uint2*)(hbn + (size_t)a*HID + c0);
#pragma unroll
      for(int x=0;x<4;x++) acc[x] = bf2f(hv.us[x]);
    }
#pragma unroll
    for(int x=0;x<4;x++) acc[x] += sl[c0+x];
    if(a == 0){
#pragma unroll
      for(int x=0;x<4;x++) acc[x] += lo[c0+x];
    }
    int s    = offsets[a];
    int send = offsets[a+1];
    for(; s+1 < send; s += 2){
      int src0 = srcC[s], src1 = srcC[s+1];
      union { uint2 v; unsigned short us[4]; } g0v, g1v;
      g0v.v = *(const uint2*)(hbn + (size_t)src0*HID + c0);
      g1v.v = *(const uint2*)(hbn + (size_t)src1*HID + c0);
#pragma unroll
      for(int x=0;x<4;x++) acc[x] += bf2f(g0v.us[x]) + bf2f(g1v.us[x]);
    }
    if(s < send){
      int src0 = srcC[s];
      union { uint2 v; unsigned short us[4]; } gv;
      gv.v = *(const uint2*)(hbn + (size_t)src0*HID + c0);
#pragma unroll
      for(int x=0;x<4;x++) acc[x] += bf2f(gv.us[x]);
    }
    union { u32x2 v; unsigned short us[4]; } pk;
#pragma unroll
    for(int x=0;x<4;x++) pk.us[x] = f2bf(acc[x]);
    __builtin_nontemporal_store(pk.v, (u32x2*)(hsum + (size_t)a*HID + c0));
  }
}

// ---------------- layer_atom: fused, MFMA-based segmented reduce ----------------
// LB(256,2) — the ONLY working register budget point (proven R15-R19):
//   no LB        -> compiler targets 64 VGPR -> catastrophic spill (R19)
//   LB(256,3)    -> 84 VGPR cap              -> spill (~200MB/dispatch, R12-R14)
//   LB(256,2)    -> 128 cap, 120 used        -> clean (WRITE == z exactly)

__global__ __launch_bounds__(256,2) void layer_atom(
    const unsigned short* __restrict__ ebC, const int* __restrict__ offsets,
    const unsigned short* __restrict__ w1T, const float* __restrict__ b1e,
    const unsigned short* __restrict__ w2T, const float* __restrict__ b2e,
    const unsigned short* __restrict__ hsum,
    const unsigned short* __restrict__ m1T, const float* __restrict__ b1n,
    const unsigned short* __restrict__ m2T, const float* __restrict__ b2n,
    float* __restrict__ z, float* __restrict__ stats, int N)
{
  __shared__ alignas(16) char SM[53248];
  unsigned short* sEB0 = (unsigned short*)SM;
  unsigned short* sHT  = (unsigned short*)(SM + 4096);
  unsigned short* sH   = (unsigned short*)(SM + 4096);
  unsigned short* sSel = (unsigned short*)(SM + 36864);
  unsigned short* sHD  = (unsigned short*)(SM + 36864);
  unsigned short* sEB1 = (unsigned short*)(SM + 45056);
  __shared__ int sOff[65];
  __shared__ int sDeg[64];
  const int t  = threadIdx.x;
  const int m0 = blockIdx.x*64;

  if(t < 65) sOff[t] = offsets[min(m0 + t, N)];
  __syncthreads();
  const int sBeg = sOff[0], sEnd = sOff[64];
  if(t < 64) sDeg[t] = sOff[t+1] - sOff[t];

  const int w = t>>6, l = t&63, lg = l>>4, lc = l&15;
  const f32x4 z4 = {0.f,0.f,0.f,0.f};

  // ---- Phase A: hidsum via sel@hid1, accumulated in MFMA C regs ----
  f32x4 hacc[4][4];
#pragma unroll
  for(int fi=0;fi<4;fi++)
#pragma unroll
    for(int fj=0;fj<4;fj++) hacc[fi][fj] = z4;

  {
    const int prow = t >> 2;
    const int pkc  = (t & 3) << 3;

    {
      int slot = sBeg + prow;
      u32x4 val = {0,0,0,0};
      if(pkc < 16 && slot < min(sBeg+64, sEnd))
        val = __builtin_nontemporal_load((const u32x4*)(ebC + (size_t)slot*16 + pkc));
      *(u32x4*)((char*)sEB0 + swzb(prow, pkc*2, 64)) = val;
    }

    int cur = 0;
    for(int sb = sBeg; sb < sEnd; sb += 64){
      const int se = min(sb + 64, sEnd);
      __syncthreads();
      unsigned short* sEBc = cur ? sEB1 : sEB0;
      unsigned short* sEBn = cur ? sEB0 : sEB1;

      const bool hasNext = (sb + 64 < sEnd);
      u32x4 nv = {0,0,0,0};
      if(hasNext){
        int slot = sb + 64 + prow;
        if(pkc < 16 && slot < min(sb+128, sEnd))
          nv = __builtin_nontemporal_load((const u32x4*)(ebC + (size_t)slot*16 + pkc));
      }

      { // stage-1 MFMA -> hid1 transposed into sHT[col][slot]
        bf16x8 a[4];
#pragma unroll
        for(int fi=0;fi<4;fi++)
          a[fi] = *(const bf16x8*)((const char*)sEBc + swzb(fi*16+lc, lg*16, 64));
#pragma unroll
        for(int fj=0;fj<4;fj++){
          bf16x8 b = *(const bf16x8*)(w1T + (size_t)(w*4+fj)*512 + l*8);
          int col = w*64 + fj*16 + lc;
          float bias = b1e[col];
#pragma unroll
          for(int fi=0;fi<4;fi++){
            f32x4 s1 = mfma16(a[fi], b, z4);
#pragma unroll
            for(int r=0;r<4;r++){
              int slot = fi*16 + lg*4 + r;
              float v = s1[r] + bias;
              v = v > 0.f ? v : 0.f;
              *(unsigned short*)((char*)sHT + swzb(col, slot*2, 128)) = f2bf(v);
            }
          }
        }
      }

      if(t < 64){
        int lo = max(sOff[t], sb) - sb;
        int hi = min(sOff[t+1], se) - sb;
#pragma unroll
        for(int g=0; g<8; g++){
          union { u32x4 v; unsigned short us[8]; } pk;
#pragma unroll
          for(int j=0;j<8;j++){
            int s = g*8 + j;
            pk.us[j] = (s >= lo && s < hi) ? (unsigned short)0x3F80 : (unsigned short)0;
          }
          *(u32x4*)((char*)sSel + swzb(t, g*16, 128)) = pk.v;
        }
      }

      if(hasNext)
        *(u32x4*)((char*)sEBn + swzb(prow, pkc*2, 64)) = nv;
      __syncthreads();

      // reduce: hacc += sel @ hid1
#pragma unroll
      for(int ks=0; ks<2; ks++){
        bf16x8 as[4], bh[4];
#pragma unroll
        for(int fi=0;fi<4;fi++)
          as[fi] = *(const bf16x8*)((const char*)sSel + swzb(fi*16+lc, (ks*32+lg*8)*2, 128));
#pragma unroll
        for(int fj=0;fj<4;fj++)
          bh[fj] = *(const bf16x8*)((const char*)sHT + swzb(w*64+fj*16+lc, (ks*32+lg*8)*2, 128));
#pragma unroll
        for(int fi=0;fi<4;fi++)
#pragma unroll
          for(int fj=0;fj<4;fj++)
            hacc[fi][fj] = mfma16(as[fi], bh[fj], hacc[fi][fj]);
      }
      cur ^= 1;
    }
  }
  __syncthreads();

  // write hidsum (bf16) into sH row-major [atom][col]
#pragma unroll
  for(int fj=0;fj<4;fj++){
    int col = w*64 + fj*16 + lc;
#pragma unroll
    for(int fi=0;fi<4;fi++)
#pragma unroll
      for(int r=0;r<4;r++){
        int row = fi*16 + lg*4 + r;
        *(unsigned short*)((char*)sH + swzb(row, col*2, 512)) = f2bf(hacc[fi][fj][r]);
      }
  }
  __syncthreads();

  // ---- Phase B1: aggr = bf16( hidsum@W2 + deg*b2e + hsum ) ----
  {
    f32x4 zacc[4][4];
#pragma unroll
    for(int fi=0;fi<4;fi++)
#pragma unroll
      for(int fj=0;fj<4;fj++) zacc[fi][fj] = z4;
    for(int k0=0;k0<256;k0+=32){
      bf16x8 a[4], b[4];
#pragma unroll
      for(int fi=0;fi<4;fi++)
        a[fi] = *(const bf16x8*)((const char*)sH + swzb(fi*16+lc, (k0+lg*8)*2, 512));
#pragma unroll
      for(int fj=0;fj<4;fj++)
        b[fj] = *(const bf16x8*)(w2T + ((size_t)(w*4+fj)*8 + (k0>>5))*512 + l*8);
#pragma unroll
      for(int fi=0;fi<4;fi++)
#pragma unroll
        for(int fj=0;fj<4;fj++)
          zacc[fi][fj] = mfma16(a[fi], b[fj], zacc[fi][fj]);
    }
    __syncthreads();

    for(int i=t; i<2048; i+=256){
      int row = i >> 5, q = i & 31;
      int gr = m0 + row;
      u32x4 v = {0,0,0,0};
      if(gr < N) v = __builtin_nontemporal_load(((const u32x4*)(hsum + (size_t)gr*HID)) + q);
      *(u32x4*)((char*)sH + swzb(row, q*16, 512)) = v;
    }
    __syncthreads();

#pragma unroll
    for(int fj=0;fj<4;fj++){
      int col = w*64 + fj*16 + lc;
      float b2c = b2e[col];
#pragma unroll
      for(int fi=0;fi<4;fi++)
#pragma unroll
        for(int r=0;r<4;r++){
          int row = fi*16 + lg*4 + r;
          unsigned short* p = (unsigned short*)((char*)sH + swzb(row, col*2, 512));
          float v = zacc[fi][fj][r] + (float)sDeg[row]*b2c + bf2f(*p);
          *p = f2bf(v);
        }
    }
  }
  __syncthreads();

  // ---- Phase B2: node MLP from sH (aggr) ----
  f32x4 nacc[4][4];
#pragma unroll
  for(int fi=0;fi<4;fi++)
#pragma unroll
    for(int fj=0;fj<4;fj++) nacc[fi][fj] = z4;

  for(int c=0;c<4;c++){
    f32x4 h1[4][2];
#pragma unroll
    for(int fi=0;fi<4;fi++){ h1[fi][0] = z4; h1[fi][1] = z4; }
    for(int k0=0;k0<256;k0+=32){
      bf16x8 a[4];
#pragma unroll
      for(int fi=0;fi<4;fi++)
        a[fi] = *(const bf16x8*)((const char*)sH + swzb(fi*16+lc, (k0+lg*8)*2, 512));
#pragma unroll
      for(int fj=0;fj<2;fj++){
        bf16x8 b = *(const bf16x8*)(m1T + ((size_t)(c*8 + w*2 + fj)*8 + (k0>>5))*512 + l*8);
#pragma unroll
        for(int fi=0;fi<4;fi++)
          h1[fi][fj] = mfma16(a[fi], b, h1[fi][fj]);
      }
    }
    __syncthreads();
#pragma unroll
    for(int fj=0;fj<2;fj++){
      int col  = c*128 + w*32 + fj*16 + lc;
      int lcol = w*32 + fj*16 + lc;
      float bias = b1n[col];
#pragma unroll
      for(int fi=0;fi<4;fi++)
#pragma unroll
        for(int r=0;r<4;r++){
          int row = fi*16 + lg*4 + r;
          float v = h1[fi][fj][r] + bias;
          v = v > 0.f ? v : 0.f;
          *(unsigned short*)((char*)sHD + swzb(row, lcol*2, 256)) = f2bf(v);
        }
    }
    __syncthreads();
    for(int k0=0;k0<128;k0+=32){
      bf16x8 a[4], b[4];
#pragma unroll
      for(int fi=0;fi<4;fi++)
        a[fi] = *(const bf16x8*)((const char*)sHD + swzb(fi*16+lc, (k0+lg*8)*2, 256));
#pragma unroll
      for(int fj=0;fj<4;fj++)
        b[fj] = *(const bf16x8*)(m2T + ((size_t)(w*4+fj)*16 + c*4 + (k0>>5))*512 + l*8);
#pragma unroll
      for(int fi=0;fi<4;fi++)
#pragma unroll
        for(int fj=0;fj<4;fj++)
          nacc[fi][fj] = mfma16(a[fi], b[fj], nacc[fi][fj]);
    }
  }

  // BN stats
  float bb[4];
#pragma unroll
  for(int fj=0;fj<4;fj++){
    int col = w*64 + fj*16 + lc;
    bb[fj] = b2n[col];
    float s1 = 0.f, s2 = 0.f;
#pragma unroll
    for(int fi=0;fi<4;fi++)
#pragma unroll
      for(int r=0;r<4;r++){
        int gr = m0 + fi*16 + lg*4 + r;
        float v = nacc[fi][fj][r] + bb[fj];
        if(gr < N){ s1 += v; s2 += v*v; }
      }
    s1 += __shfl_xor(s1, 16, 64); s1 += __shfl_xor(s1, 32, 64);
    s2 += __shfl_xor(s2, 16, 64); s2 += __shfl_xor(s2, 32, 64);
    if(lg == 0){
      atomicAdd(&stats[col],       s1);
      atomicAdd(&stats[HID + col], s2);
    }
  }

  // z write restaged through LDS
  float* sZF = (float*)SM;   // [32][260] f32 = 33280 B
#pragma unroll
  for(int half=0; half<2; half++){
    __syncthreads();
#pragma unroll
    for(int fj=0;fj<4;fj++){
      int col = w*64 + fj*16 + lc;
#pragma unroll
      for(int fp=0;fp<2;fp++){
        int fi = half*2 + fp;
#pragma unroll
        for(int r=0;r<4;r++){
          int row32 = fp*16 + lg*4 + r;
          sZF[row32*260 + col] = nacc[fi][fj][r] + bb[fj];
        }
      }
    }
    __syncthreads();
    for(int i=t; i<2048; i+=256){
      int row = i >> 6, seg = i & 63;
      int gr = m0 + half*32 + row;
      if(gr < N){
        u32x4 v = *(const u32x4*)(sZF + row*260 + seg*4);
        __builtin_nontemporal_store(v, (u32x4*)(z + (size_t)gr*HID + seg*4));
      }
    }
  }
}

// final BN applied in-place to out; BN params finalized inline from raw stats
__global__ void final_bn(float* __restrict__ out,
                         const float* __restrict__ stats, float invN,
                         const float* __restrict__ gamma, const float* __restrict__ beta,
                         long total4){
  for(long i = (long)blockIdx.x*blockDim.x + threadIdx.x; i < total4; i += (long)gridDim.x*blockDim.x){
    int c0 = ((int)(i & 63)) << 2;
    float4 v = ((const float4*)out)[i];
    float o[4] = {v.x, v.y, v.z, v.w};
#pragma unroll
    for(int c=0;c<4;c++){
      float mu  = stats[c0+c] * invN;
      float var = stats[HID + c0 + c] * invN - mu*mu;
      float rs  = rsqrtf(var + BN_EPS);
      o[c] = gamma[c0+c]*(o[c] - mu)*rs + beta[c0+c];
    }
    float4 ov = {o[0], o[1], o[2], o[3]};
    ((float4*)out)[i] = ov;
  }
}

// ---------------- host ----------------
// Workspace ~177 MB. Intermediate z lives in d_out. stats_fin/musig removed:
// BN finalize math recomputed inline in bn_relu_pack/final_bn (bit-identical).

extern "C" void kernel_launch(void* const* d_in, const int* in_sizes, int n_in,
                              void* d_out, int out_size, void* d_ws, size_t ws_size,
                              hipStream_t stream)
{
  const float* f_atoms = (const float*)d_in[0];
  const float* f_bonds = (const float*)d_in[1];
  const int*   a2b     = (const int*)d_in[2];
  const int*   b2a     = (const int*)d_in[3];
  const float* w_atom  = (const float*)d_in[6];
  const float* wb_w1   = (const float*)d_in[7];
  const float* wb_b1   = (const float*)d_in[8];
  const float* wb_w2   = (const float*)d_in[9];
  const float* wb_b2   = (const float*)d_in[10];
  const float* mlp_w1  = (const float*)d_in[11];
  const float* mlp_b1  = (const float*)d_in[12];
  const float* mlp_w2  = (const float*)d_in[13];
  const float* mlp_b2  = (const float*)d_in[14];
  const float* bn_g    = (const float*)d_in[15];
  const float* bn_b    = (const float*)d_in[16];
  const int N = in_sizes[0] / AFD;
  const int E = in_sizes[3];
  float* out = (float*)d_out;
  (void)n_in; (void)out_size; (void)ws_size;

  char* ws = (char*)d_ws;
  size_t off = 0;
  auto alloc = [&](size_t bytes)->char* {
    char* p = ws + off; off += (bytes + 255) & ~(size_t)255; return p;
  };
  unsigned short* hbn   = (unsigned short*)alloc((size_t)N*HID*2);
  unsigned short* hsum  = (unsigned short*)alloc((size_t)N*HID*2);
  unsigned short* ebC   = (unsigned short*)alloc((size_t)E*16*2);
  int* srcC             = (int*)alloc((size_t)E*4);
  int* b2slot           = (int*)alloc((size_t)E*4);
  int* slot2b           = (int*)alloc((size_t)E*4);
  int* offsets          = (int*)alloc((size_t)(N+1)*4);
  int* offs_local       = (int*)alloc((size_t)N*4);
  int* partials         = (int*)alloc((size_t)512*4);
  int* total            = (int*)alloc((size_t)4);
  int* unc              = (int*)alloc((size_t)(1+UNC_CAP)*4);
  unsigned short* wAT   = (unsigned short*)alloc((size_t)HID*KA_PAD*2);
  unsigned short* w1T   = (unsigned short*)alloc((size_t)3*HID*KB_PAD*2);
  unsigned short* w2T   = (unsigned short*)alloc((size_t)3*HID*HID*2);
  unsigned short* m1T   = (unsigned short*)alloc((size_t)3*512*HID*2);
  unsigned short* m2T   = (unsigned short*)alloc((size_t)3*HID*512*2);
  float* sl             = (float*)alloc((size_t)3*HID*4);
  float* stats          = (float*)alloc((size_t)3*512*4);
  float* lo             = (float*)alloc((size_t)3*HID*4);

  hipMemsetAsync(stats,  0,    (size_t)3*512*4, stream);
  hipMemsetAsync(b2slot, 0xFF, (size_t)E*4, stream);
  hipMemsetAsync(unc,    0,    (size_t)(1+UNC_CAP)*4, stream);

  auto cdiv = [](long a, long b){ return (int)((a + b - 1)/b); };
  const int nb = cdiv(N, 256);
  const float invN = 1.0f/(float)N;

  count_scan<<<nb,256,0,stream>>>(a2b, offs_local, partials, N);
  scan_partials<<<1,512,0,stream>>>(partials, nb, total);
  add_base<<<512,256,0,stream>>>(offs_local, partials, total, offsets, N);
  build_slot<<<2048,256,0,stream>>>(a2b, offsets, b2slot, slot2b, N);
  reorder_csr<<<2048,256,0,stream>>>(slot2b, total, f_bonds, b2a, ebC, srcC);
  build_unc<<<2048,256,0,stream>>>(b2slot, unc, E);

  pack_all<<<2048,256,0,stream>>>(w_atom, wb_w1, wb_w2, mlp_w1, mlp_w2,
                                  wAT, w1T, w2T, m1T, m2T);
  sl_emb_kernel<<<3,256,0,stream>>>(wb_w1, wb_b1, wb_w2, wb_b2, sl);

  atom_embed<<<cdiv(N,64),256,0,stream>>>(f_atoms, wAT, hbn, N);

  for(int l=0;l<3;l++){
    if(l > 0){
      bn_relu_pack<<<2048,256,0,stream>>>(out, stats + (size_t)(l-1)*512, invN,
          bn_g + (size_t)(l-1)*HID, bn_b + (size_t)(l-1)*HID, hbn, (long)N*32);
    }
    leftover_mlp<<<1,256,0,stream>>>(f_bonds, b2a, unc,
        w1T + (size_t)l*HID*KB_PAD, wb_b1 + (size_t)l*HID,
        w2T + (size_t)l*HID*HID,    wb_b2 + (size_t)l*HID,
        hbn, lo + (size_t)l*HID);
    hsum_gather<<<2048,256,0,stream>>>(offsets, srcC, hbn,
        sl + (size_t)l*HID, lo + (size_t)l*HID, hsum, N);
    layer_atom<<<cdiv(N,64),256,0,stream>>>(ebC, offsets,
        w1T + (size_t)l*HID*KB_PAD, wb_b1 + (size_t)l*HID,
        w2T + (size_t)l*HID*HID,    wb_b2 + (size_t)l*HID,
        hsum,
        m1T + (size_t)l*512*HID, mlp_b1 + (size_t)l*512,
        m2T + (size_t)l*HID*512, mlp_b2 + (size_t)l*HID,
        out, stats + (size_t)l*512, N);
  }
  final_bn<<<2048,256,0,stream>>>(out, stats + 2*512, invN,
                                  bn_g + 2*HID, bn_b + 2*HID, (long)N*64);
}